// Round 2
// baseline (324.000 us; speedup 1.0000x reference)
//
#include <hip/hip_runtime.h>
#include <math.h>

#define B_    2
#define L_    2048
#define D_    768
#define K_    12
#define KQ_   6
#define M_    4
#define H_    64
#define ZC_   780      // MEM + K
#define NTOK_ 4096     // B*L
#define NC_   64       // scan chunks per batch
#define LC_   32       // chunk length (L/NC)
#define QST_  3072     // q fp16 row stride
#define XPN_  4352     // merged projection N (padded to 17*256 for 256-tile GEMM)

typedef __attribute__((ext_vector_type(8))) _Float16 half8;
typedef __attribute__((ext_vector_type(4))) float f32x4;

__device__ __forceinline__ float softplus_f(float x) {
  return (x > 20.f) ? x : log1pf(expf(x));
}

__device__ __forceinline__ float fast_tanh(float x) {
  float xx = fminf(fmaxf(x, -10.f), 10.f);
  float e = __expf(2.f * xx);
  return (e - 1.f) / (e + 1.f);
}

// async global->LDS 16B per lane (dest = wave-uniform base + lane*16)
__device__ __forceinline__ void async16(const _Float16* g, _Float16* l) {
  __builtin_amdgcn_global_load_lds(
      (const __attribute__((address_space(1))) unsigned int*)g,
      (__attribute__((address_space(3))) unsigned int*)l, 16, 0, 0);
}

// val/gate 16-interleave permutation for spec-B columns
__device__ __forceinline__ int permcol(int n) {
  int isg = (n >= 192) ? 1 : 0;
  int j = n - 192 * isg;
  return (j >> 4) * 32 + (isg << 4) + (j & 15);
}

#define FENCE() asm volatile("" ::: "memory")

// ---------------------------------------------------------------------------
// Transpose+convert body; optional perm + scale
// ---------------------------------------------------------------------------
__device__ __forceinline__ void cvt_t_body(float (*tile)[33], int bx, int by, int kz,
                                           const float* src, long sKs, int srs,
                                           _Float16* dh, long dKs, int dst, int doff,
                                           int R, int Nact, bool perm, float scale) {
  const float* s = src + (size_t)kz * sKs;
  _Float16* dhh = dh + (size_t)kz * dKs;
  const int kb = bx * 32;
  const int nb = by * 32;
  const int tx = threadIdx.x & 31, ty = threadIdx.x >> 5;
  for (int i = ty; i < 32; i += 8) {
    int kk = kb + i, n = nb + tx;
    tile[i][tx] = (kk < R && n < Nact) ? s[(size_t)kk * srs + n] : 0.f;
  }
  __syncthreads();
  for (int i = ty; i < 32; i += 8) {
    int n = nb + i, kk = kb + tx;
    if (kk < R) {
      float v = tile[tx][i] * scale;
      int dn = perm ? permcol(n) : n;
      dhh[(size_t)dn * dst + doff + kk] = (_Float16)v;
    }
  }
}

// ---------------------------------------------------------------------------
// Fused prologue, ONE dispatch:
//   blocks [0,3):          precomp (theta/w tables, slopes)
//   blocks [3,6363):       all weight conversions (incl. gate_W -> xpb cols)
//   blocks [6363,18651):   out zero-fill + x f32->fp16
// xpb layout (rows x 768): [W_q^T 0:3072 | skd^T 3072:3264 | gate^T 3264:3276 |
//                           pad | W_mem^T 3328:4108 | pad to 4352]
// ---------------------------------------------------------------------------
__global__ __launch_bounds__(256)
void prep_kernel(const float* __restrict__ x,
                 const float* __restrict__ W_mem, const float* __restrict__ W_q,
                 const float* __restrict__ skip_down_W, const float* __restrict__ out_W,
                 const float* __restrict__ W_re, const float* __restrict__ W_im,
                 const float* __restrict__ skip_up_W, const float* __restrict__ hs,
                 const float* __restrict__ gate_W,
                 const float* __restrict__ theta_d_raw, const float* __restrict__ decay,
                 float* __restrict__ out, _Float16* __restrict__ x_h,
                 _Float16* __restrict__ xpb_h, _Float16* __restrict__ outw_h,
                 _Float16* __restrict__ bsp_h,
                 float* __restrict__ theta_tab, float* __restrict__ w_tab,
                 float* __restrict__ slopes_sp) {
  __shared__ float tile[32][33];
  int b = blockIdx.x;
  if (b < 3) {
    int idx = b * 256 + threadIdx.x;
    if (idx < K_) slopes_sp[idx] = softplus_f(decay[idx]);
    if (idx >= K_ * H_) return;
    float td[M_], ta[M_];
#pragma unroll
    for (int m = 0; m < M_; ++m) td[m] = softplus_f(theta_d_raw[idx * M_ + m]) + 1e-4f;
    ta[0] = td[0];
#pragma unroll
    for (int m = 1; m < M_; ++m) ta[m] = ta[m - 1] + td[m];
    float total = ta[M_ - 1];
    float rs = 2.999f / total;
#pragma unroll
    for (int m = 0; m < M_; ++m) theta_tab[idx * M_ + m] = 0.001f + ta[m] * rs;
    float d0 = (ta[1] - ta[0]) * rs;
    float d1 = (ta[2] - ta[1]) * rs;
    float d2 = (ta[3] - ta[2]) * rs;
    w_tab[idx * M_ + 0] = 0.5f * d0;
    w_tab[idx * M_ + 1] = 0.5f * (d0 + d1);
    w_tab[idx * M_ + 2] = 0.5f * (d1 + d2);
    w_tab[idx * M_ + 3] = 0.5f * d2;
    return;
  }
  b -= 3;
  if (b < 6360) {
    if (b < 672) {           // W_mem -> xpb rows [3328,4108), 24x28
      cvt_t_body(tile, b % 24, b / 24, 0, W_mem, 0, ZC_, xpb_h + (size_t)3328 * 768,
                 0, 768, 0, 768, ZC_, false, 1.f);
      return;
    }
    b -= 672;
    if (b < 2304) {          // W_q -> xpb rows [0,3072), 24x96
      cvt_t_body(tile, b % 24, b / 24, 0, W_q, 0, 3072, xpb_h, 0, 768, 0, 768, 3072, false, 1.f);
      return;
    }
    b -= 2304;
    if (b < 192) {           // skip_down -> xpb rows [3072,3264), 24x8
      cvt_t_body(tile, b % 24, b / 24, 0, skip_down_W, 0, 192, xpb_h + (size_t)3072 * 768,
                 0, 768, 0, 768, 192, false, 1.f);
      return;
    }
    b -= 192;
    if (b < 1728) {          // out_W -> outw, 72x24
      cvt_t_body(tile, b % 72, b / 72, 0, out_W, 0, 768, outw_h, 0, 2304, 0, 2304, 768, false, 1.f);
      return;
    }
    b -= 1728;
    if (b < 288) {           // W_re -> bsp[k][perm(n)][0:64], 2x12x12
      cvt_t_body(tile, b % 2, (b / 2) % 12, b / 24, W_re, 64L * 384, 384, bsp_h,
                 384L * 320, 320, 0, 64, 384, true, 1.f);
      return;
    }
    b -= 288;
    if (b < 288) {           // W_im -> bsp[k][perm(n)][64:128]
      cvt_t_body(tile, b % 2, (b / 2) % 12, b / 24, W_im, 64L * 384, 384, bsp_h,
                 384L * 320, 320, 64, 64, 384, true, 1.f);
      return;
    }
    b -= 288;
    if (b < 864) {           // skip_up slice -> bsp[k][perm(n)][128:320] scaled by hs[k]
      int kz = b / 72;
      cvt_t_body(tile, b % 6, (b / 6) % 12, kz, skip_up_W, 384, 4608, bsp_h,
                 384L * 320, 320, 128, 192, 384, true, hs[kz]);
      return;
    }
    b -= 864;
    // gate_W (768x12) -> xpb rows [3264,3276), 24 blocks
    cvt_t_body(tile, b, 0, 0, gate_W, 0, K_, xpb_h + (size_t)3264 * 768,
               0, 768, 0, 768, K_, false, 1.f);
    return;
  }
  b -= 6360;
  size_t i = (size_t)b * 256 + threadIdx.x;
  if (i < (size_t)NTOK_ * D_) {
    out[i] = 0.f;                    // zero split-K atomic target
    x_h[i] = (_Float16)x[i];         // x -> fp16
  }
}

// ---------------------------------------------------------------------------
// 256x256-tile 8-phase deep-pipelined MFMA GEMM for the merged x-projection.
// M=4096, N=4352 (padded), K=768, BK=64, 12 K-tiles, 512 threads (8 waves 2Mx4N),
// 128 KiB dbuf LDS. Per K-tile: 4 phases x 16 MFMA/wave; register subtiles read
// one phase ahead; half-tiles staged with 3-4 phase flight; ONE vmcnt drain per
// K-tile placed BEFORE a barrier (cross-wave DMA visibility). Stage targets only
// overwrite LDS whose last read was >=2 phases earlier (barrier-ordered safe).
// Epilogue: col<3072 -> QH fp16; [3072,3264) -> YH fp16 (lat); [3264,3276) -> GL
// f32 (gate linear); [3328,4108) -> C f32 (z_pre); else skip.
// ---------------------------------------------------------------------------
__global__ __launch_bounds__(512, 2)
void xproj256_kernel(const _Float16* __restrict__ Ah, const _Float16* __restrict__ Bh,
                     float* __restrict__ C, _Float16* __restrict__ YH,
                     _Float16* __restrict__ QH, float* __restrict__ GL) {
  __shared__ __align__(16) _Float16 sA[2][2][128][64];
  __shared__ __align__(16) _Float16 sB[2][2][128][64];

  // bijective XCD chunking: 272 blocks = 8 xcd x 34; xcd owns 2 by-rows x 17 bx
  const int bid = blockIdx.x;
  const int xcd = bid & 7, s = bid >> 3;        // s in [0,34)
  const int by = xcd * 2 + (s & 1);             // 0..15
  const int bx = s >> 1;                        // 0..16
  const int bm0 = by * 256, bn0 = bx * 256;

  const int tid = threadIdx.x;
  const int lane = tid & 63;
  const int wave = tid >> 6;
  const int m16 = lane & 15, quad = lane >> 4;
  const int wr = wave >> 2;          // 0..1 A-half
  const int wc = wave & 3;           // 0..3 B col group (64 cols)
  const int bhalf = wc >> 1;         // B LDS half
  const int brow0 = (wc & 1) * 64;   // row base within B half

  f32x4 acc[8][4];
#pragma unroll
  for (int i = 0; i < 8; ++i)
#pragma unroll
    for (int j = 0; j < 4; ++j) acc[i][j] = (f32x4){0.f, 0.f, 0.f, 0.f};

  // staging geometry: thread covers physical 16B block pb of row r0 (+64)
  const int r0 = tid >> 3;
  const int pb = tid & 7, ps = pb & 3, hseg = pb >> 2;
  const int swz0 = (r0 >> 1) & 3;    // same for r0 and r0+64

  auto stageA = [&](int t, int h) {
    _Float16* dst = &sA[t & 1][h][0][0];
    const _Float16* srow = Ah + (size_t)(bm0 + h * 128) * 768 + t * 64
                           + hseg * 32 + ((ps ^ swz0) << 3);
    async16(srow + (size_t)r0 * 768, dst + tid * 8);
    async16(srow + (size_t)(r0 + 64) * 768, dst + 4096 + tid * 8);
  };
  auto stageB = [&](int t, int h) {
    _Float16* dst = &sB[t & 1][h][0][0];
    const _Float16* srow = Bh + (size_t)(bn0 + h * 128) * 768 + t * 64
                           + hseg * 32 + ((ps ^ swz0) << 3);
    async16(srow + (size_t)r0 * 768, dst + tid * 8);
    async16(srow + (size_t)(r0 + 64) * 768, dst + 4096 + tid * 8);
  };

  auto ldA = [&](int bb, int r, int kk) -> half8 {
    return *(const half8*)&sA[bb][wr][r][kk * 32 + ((quad ^ ((r >> 1) & 3)) << 3)];
  };
  auto ldB = [&](int bb, int r, int kk) -> half8 {
    return *(const half8*)&sB[bb][bhalf][r][kk * 32 + ((quad ^ ((r >> 1) & 3)) << 3)];
  };

  half8 aLo[8], aHi[8], bLo[4], bHi[4];

  // ---- prologue: stage K-tiles 0 and 1 (B before A, matching steady order)
  stageB(0, 0); stageB(0, 1); stageA(0, 0); stageA(0, 1);
  stageB(1, 0); stageB(1, 1); stageA(1, 0); stageA(1, 1);
  __builtin_amdgcn_s_waitcnt(0x0F78);   // vmcnt(8): K-tile 0 landed
  FENCE(); __builtin_amdgcn_s_barrier(); FENCE();
  // pre-reads for phase (0,0): aLo(0), bLo(0)
#pragma unroll
  for (int m = 0; m < 4; ++m)
#pragma unroll
    for (int kk = 0; kk < 2; ++kk) aLo[m * 2 + kk] = ldA(0, m * 16 + m16, kk);
#pragma unroll
  for (int n = 0; n < 2; ++n)
#pragma unroll
    for (int kk = 0; kk < 2; ++kk) bLo[n * 2 + kk] = ldB(0, brow0 + n * 16 + m16, kk);

  for (int t = 0; t < 12; ++t) {
    const int bb = t & 1;
    const int nb = bb ^ 1;
    // ---------- phase 0: read bHi(t); MFMA lo-lo ----------
#pragma unroll
    for (int n = 0; n < 2; ++n)
#pragma unroll
      for (int kk = 0; kk < 2; ++kk)
        bHi[n * 2 + kk] = ldB(bb, brow0 + (n + 2) * 16 + m16, kk);
    FENCE(); __builtin_amdgcn_s_barrier(); FENCE();
    __builtin_amdgcn_s_setprio(1);
#pragma unroll
    for (int m = 0; m < 4; ++m)
#pragma unroll
      for (int n = 0; n < 2; ++n)
#pragma unroll
        for (int kk = 0; kk < 2; ++kk)
          acc[m][n] = __builtin_amdgcn_mfma_f32_16x16x32_f16(aLo[m * 2 + kk], bLo[n * 2 + kk],
                                                             acc[m][n], 0, 0, 0);
    __builtin_amdgcn_s_setprio(0);
    FENCE(); __builtin_amdgcn_s_barrier(); FENCE();
    // ---------- phase 1: read aHi(t); MFMA lo-hi; drain vmcnt (once/K-tile) ----------
#pragma unroll
    for (int m = 0; m < 4; ++m)
#pragma unroll
      for (int kk = 0; kk < 2; ++kk)
        aHi[m * 2 + kk] = ldA(bb, 64 + m * 16 + m16, kk);
    FENCE(); __builtin_amdgcn_s_barrier(); FENCE();
    __builtin_amdgcn_s_setprio(1);
#pragma unroll
    for (int m = 0; m < 4; ++m)
#pragma unroll
      for (int n = 2; n < 4; ++n)
#pragma unroll
        for (int kk = 0; kk < 2; ++kk)
          acc[m][n] = __builtin_amdgcn_mfma_f32_16x16x32_f16(aLo[m * 2 + kk], bHi[(n - 2) * 2 + kk],
                                                             acc[m][n], 0, 0, 0);
    __builtin_amdgcn_s_setprio(0);
    __builtin_amdgcn_s_waitcnt(0x0F70);   // vmcnt(0): K-tile t+1 landed (3-4 phase flight)
    FENCE(); __builtin_amdgcn_s_barrier(); FENCE();
    // ---------- phase 2: read aLo(t+1); stage B(t+2); MFMA hi-lo ----------
    if (t < 11) {
#pragma unroll
      for (int m = 0; m < 4; ++m)
#pragma unroll
        for (int kk = 0; kk < 2; ++kk)
          aLo[m * 2 + kk] = ldA(nb, m * 16 + m16, kk);
    }
    if (t < 10) { stageB(t + 2, 0); stageB(t + 2, 1); }
    FENCE(); __builtin_amdgcn_s_barrier(); FENCE();
    __builtin_amdgcn_s_setprio(1);
#pragma unroll
    for (int m = 0; m < 4; ++m)
#pragma unroll
      for (int n = 0; n < 2; ++n)
#pragma unroll
        for (int kk = 0; kk < 2; ++kk)
          acc[m + 4][n] = __builtin_amdgcn_mfma_f32_16x16x32_f16(aHi[m * 2 + kk], bLo[n * 2 + kk],
                                                                 acc[m + 4][n], 0, 0, 0);
    __builtin_amdgcn_s_setprio(0);
    FENCE(); __builtin_amdgcn_s_barrier(); FENCE();
    // ---------- phase 3: read bLo(t+1); stage A(t+2); MFMA hi-hi ----------
    if (t < 11) {
#pragma unroll
      for (int n = 0; n < 2; ++n)
#pragma unroll
        for (int kk = 0; kk < 2; ++kk)
          bLo[n * 2 + kk] = ldB(nb, brow0 + n * 16 + m16, kk);
    }
    if (t < 10) { stageA(t + 2, 0); stageA(t + 2, 1); }
    FENCE(); __builtin_amdgcn_s_barrier(); FENCE();
    __builtin_amdgcn_s_setprio(1);
#pragma unroll
    for (int m = 0; m < 4; ++m)
#pragma unroll
      for (int n = 2; n < 4; ++n)
#pragma unroll
        for (int kk = 0; kk < 2; ++kk)
          acc[m + 4][n] = __builtin_amdgcn_mfma_f32_16x16x32_f16(aHi[m * 2 + kk], bHi[(n - 2) * 2 + kk],
                                                                 acc[m + 4][n], 0, 0, 0);
    __builtin_amdgcn_s_setprio(0);
    FENCE(); __builtin_amdgcn_s_barrier(); FENCE();
  }

  // ---- epilogue (C/D layout: col=lane&15, row=quad*4+reg) ----
#pragma unroll
  for (int m = 0; m < 8; ++m) {
    const int row0 = bm0 + wr * 128 + m * 16 + quad * 4;
#pragma unroll
    for (int n = 0; n < 4; ++n) {
      const int col = bn0 + wc * 64 + n * 16 + m16;
      if (col < 3072) {
#pragma unroll
        for (int r = 0; r < 4; ++r)
          QH[(size_t)(row0 + r) * QST_ + col] = (_Float16)acc[m][n][r];
      } else if (col < 3264) {
        const int jj = col - 3072;
#pragma unroll
        for (int r = 0; r < 4; ++r)
          YH[(size_t)(row0 + r) * 192 + jj] = (_Float16)acc[m][n][r];
      } else if (col < 3276) {
        const int kk = col - 3264;
#pragma unroll
        for (int r = 0; r < 4; ++r)
          GL[(size_t)(row0 + r) * K_ + kk] = acc[m][n][r];
      } else if (col >= 3328 && col < 3328 + ZC_) {
        const int wz = col - 3328;
#pragma unroll
        for (int r = 0; r < 4; ++r)
          C[(size_t)(row0 + r) * ZC_ + wz] = acc[m][n][r];
      }
    }
  }
}

// ---------------------------------------------------------------------------
// MFMA fp16 GEMM (128x128, 2-phase): kept for spec GEMM and out GEMM.
// EPI=0: f32 store. ATOMIC=1: 1D XCD-swizzled grid (gx,gy,nsplit), atomicAdd.
// EPI=1: spec GEMM: A from split source; fused val/gate SiLU -> YH; XCD-chunked.
// ---------------------------------------------------------------------------
template <int ATOMIC, int EPI>
__global__ __launch_bounds__(256)
void mfma_gemm_kernel(const _Float16* __restrict__ Ah, const _Float16* __restrict__ Bh,
                      float* __restrict__ C,
                      int Kd, int Nact,
                      long strideA, long strideB, long strideC,
                      const _Float16* __restrict__ A2, _Float16* __restrict__ YH,
                      int gx, int gy, int nsplit) {
  __shared__ __align__(16) _Float16 sA[2][128 * 32];
  __shared__ __align__(16) _Float16 sB[2][128 * 32];
  int bx, by, kz, kbeg, kend;
  if (ATOMIC) {
    int bid = blockIdx.x;
    int xcd = bid & 7, s = bid >> 3;
    bx = s % gx;
    int yz = s / gx;
    int p = xcd + 8 * yz;
    by = p % gy;
    int zz = p / gy;
    kz = 0;
    int len = Kd / nsplit;
    kbeg = zz * len;
    kend = kbeg + len;
  } else if (EPI == 1) {
    // 1152 blocks = 3bx x 32by x 12kz; XCD x owns by in [4x,4x+4) for all kz
    int bid = blockIdx.x;
    int xcd = bid & 7, s = bid >> 3;        // s in [0,144)
    kz = s / 12;
    int w = s % 12;
    bx = w % 3;
    by = (xcd << 2) + w / 3;
    kbeg = 0; kend = Kd;
  } else {
    bx = blockIdx.x; by = blockIdx.y; kz = blockIdx.z;
    kbeg = 0; kend = Kd;
  }
  const _Float16* A0 = Ah + (size_t)kz * strideA;
  const _Float16* B0 = Bh + (size_t)kz * strideB;
  float* Cb = C + (size_t)kz * strideC;
  const int bm0 = by * 128;
  const int bn0 = bx * 128;
  const int tid = threadIdx.x;
  const int wave = tid >> 6, lane = tid & 63;
  const int m16 = lane & 15, quad = lane >> 4;
  const int wr = (wave & 1) * 64, wc = (wave >> 1) * 64;

  f32x4 acc[4][4];
#pragma unroll
  for (int i = 0; i < 4; ++i)
#pragma unroll
    for (int j = 0; j < 4; ++j) acc[i][j] = (f32x4){0.f, 0.f, 0.f, 0.f};

  const int lin = tid * 8;
  const int lrow = lin >> 5;
  const int lblk = (lin >> 3) & 3;
  const int csw = ((lblk ^ ((lrow >> 1) & 3)) << 3);

  auto stage = [&](int k0, int kb) {
    if constexpr (EPI == 1) {
      if (k0 < 128) {
        const _Float16* gA = A0 + (size_t)(bm0 + lrow) * 128 + (k0 + csw);
        async16(gA, &sA[kb][lin]);
        async16(gA + (size_t)64 * 128, &sA[kb][lin + 2048]);
      } else {
        const _Float16* gA = A2 + (size_t)(bm0 + lrow) * 192 + (k0 - 128 + csw);
        async16(gA, &sA[kb][lin]);
        async16(gA + (size_t)64 * 192, &sA[kb][lin + 2048]);
      }
    } else {
      const _Float16* gA = A0 + (size_t)(bm0 + lrow) * Kd + (k0 + csw);
      async16(gA, &sA[kb][lin]);
      async16(gA + (size_t)64 * Kd, &sA[kb][lin + 2048]);
    }
    const _Float16* gB = B0 + (size_t)(bn0 + lrow) * Kd + (k0 + csw);
    async16(gB, &sB[kb][lin]);
    async16(gB + (size_t)64 * Kd, &sB[kb][lin + 2048]);
  };

  const int niter = (kend - kbeg) / 32;
  stage(kbeg, 0);
  if (niter > 1) stage(kbeg + 32, 1);

  for (int it = 0; it < niter; ++it) {
    if (it == niter - 1)
      __builtin_amdgcn_s_waitcnt(0x0F70);   // vmcnt(0)
    else
      __builtin_amdgcn_s_waitcnt(0x0F74);   // vmcnt(4)
    __builtin_amdgcn_s_barrier();
    asm volatile("" ::: "memory");
    const int kb = it & 1;
    half8 a0[4], b0[4];
#pragma unroll
    for (int i = 0; i < 4; ++i) {
      const int rA = wr + i * 16 + m16;
      a0[i] = *(const half8*)&sA[kb][rA * 32 + ((quad ^ ((rA >> 1) & 3)) << 3)];
    }
#pragma unroll
    for (int j = 0; j < 4; ++j) {
      const int rB = wc + j * 16 + m16;
      b0[j] = *(const half8*)&sB[kb][rB * 32 + ((quad ^ ((rB >> 1) & 3)) << 3)];
    }
#pragma unroll
    for (int i = 0; i < 4; ++i)
#pragma unroll
      for (int j = 0; j < 4; ++j)
        acc[i][j] = __builtin_amdgcn_mfma_f32_16x16x32_f16(a0[i], b0[j], acc[i][j], 0, 0, 0);
    asm volatile("" ::: "memory");
    __builtin_amdgcn_s_barrier();
    asm volatile("" ::: "memory");
    if (it + 2 < niter) stage(kbeg + (it + 2) * 32, kb);
  }

  if constexpr (EPI == 1) {
#pragma unroll
    for (int i = 0; i < 4; ++i) {
      const int row0 = bm0 + wr + i * 16 + quad * 4;
#pragma unroll
      for (int j = 0; j < 4; j += 2) {
        const int colv = bn0 + wc + j * 16 + m16;
        const int jout = (colv >> 5) * 16 + m16;
#pragma unroll
        for (int r = 0; r < 4; ++r) {
          float val = acc[i][j][r];
          float g = acc[i][j + 1][r];
          float sg = g / (1.f + __expf(-g));
          YH[(size_t)(row0 + r) * 2304 + kz * 192 + jout] = (_Float16)(val * sg);
        }
      }
    }
  } else {
#pragma unroll
    for (int i = 0; i < 4; ++i) {
      const int row0 = bm0 + wr + i * 16 + quad * 4;
#pragma unroll
      for (int j = 0; j < 4; ++j) {
        const int col = bn0 + wc + j * 16 + m16;
        if (col < Nact) {
#pragma unroll
          for (int r = 0; r < 4; ++r) {
            if (ATOMIC)
              atomicAdd(&Cb[(size_t)(row0 + r) * Nact + col], acc[i][j][r]);
            else
              Cb[(size_t)(row0 + r) * Nact + col] = acc[i][j][r];
          }
        }
      }
    }
  }
}

// ---------------------------------------------------------------------------
// Scan pass A with fused causal conv (sliding 4-tap window over z_pre)
// ---------------------------------------------------------------------------
__global__ void pass_a_kernel(const float* __restrict__ zp,
                              const float* __restrict__ ck,
                              const float* __restrict__ theta_tab,
                              const float* __restrict__ score_scale,
                              const float* __restrict__ tanh_scale,
                              const float* __restrict__ slopes_sp,
                              float* __restrict__ csums) {
  const int c = blockIdx.x, k = blockIdx.y, b = blockIdx.z;
  const int tid = threadIdx.x;
  const int m = tid & 3, h = tid >> 2;
  const int chk = k * H_ + h;
  const int chs = 768 + k;
  const float theta_v = theta_tab[chk * M_ + m];
  const float ts = tanh_scale[k], ss = score_scale[k], slope = slopes_sp[k];
  float ckv[4], cks[4];
#pragma unroll
  for (int w = 0; w < 4; ++w) { ckv[w] = ck[w * ZC_ + chk]; cks[w] = ck[w * ZC_ + chs]; }
  const int l0 = c * LC_;
  float zk3 = 0.f, zk2 = 0.f, zk1 = 0.f, zs3 = 0.f, zs2 = 0.f, zs1 = 0.f;
#pragma unroll
  for (int p = 0; p < 3; ++p) {
    int lp = l0 - 3 + p;
    if (lp >= 0) {
      size_t tp = (size_t)b * L_ + lp;
      float zk = zp[tp * ZC_ + chk], zs = zp[tp * ZC_ + chs];
      if (p == 0) { zk3 = zk; zs3 = zs; }
      else if (p == 1) { zk2 = zk; zs2 = zs; }
      else { zk1 = zk; zs1 = zs; }
    }
  }
  float sre = 0.f, sim = 0.f, dacc = 0.f;
  for (int ll = 0; ll < LC_; ++ll) {
    int l = l0 + ll;
    size_t t = (size_t)b * L_ + l;
    float zk0 = zp[t * ZC_ + chk];
    float zs0 = zp[t * ZC_ + chs];
    float kv = zk3 * ckv[0] + zk2 * ckv[1] + zk1 * ckv[2] + zk0 * ckv[3];
    float sraw = zs3 * cks[0] + zs2 * cks[1] + zs1 * cks[2] + zs0 * cks[3];
    zk3 = zk2; zk2 = zk1; zk1 = zk0;
    zs3 = zs2; zs2 = zs1; zs1 = zs0;
    float lp = fminf(fmaxf(ss * sraw, -20.f), 20.f);
    float pw = __expf(lp - slope * (float)(L_ - 1 - l));
    float ph = fast_tanh(ts * kv) * theta_v;
    float kvp = kv * pw;
    sre += kvp * __cosf(ph);
    sim += kvp * __sinf(ph);
    dacc += pw;
  }
  size_t base = (((size_t)b * K_ + k) * NC_ + c) * 513;
  if (tid == 0) csums[base] = dacc;
  csums[base + 1 + h * 4 + m] = sre;
  csums[base + 1 + 256 + h * 4 + m] = sim;
}

// ---------------------------------------------------------------------------
__global__ void pass_b_kernel(const float* __restrict__ csums,
                              float* __restrict__ cpre) {
  int bk = blockIdx.y;
  int comp = blockIdx.x * 64 + threadIdx.x;
  if (comp >= 513) return;
  float run = 0.f;
  size_t base = (size_t)bk * NC_ * 513 + comp;
  for (int c = 0; c < NC_; ++c) {
    cpre[base + (size_t)c * 513] = run;
    run += csums[base + (size_t)c * 513];
  }
}

// ---------------------------------------------------------------------------
// Scan pass C: fused conv replay, contract with fp16 q, apply ns*gate,
// write fp16 into asp2[k][t][0:128] (128-stride)
// ---------------------------------------------------------------------------
__global__ void pass_c_kernel(const float* __restrict__ zp,
                              const float* __restrict__ ck,
                              const _Float16* __restrict__ qh,
                              const float* __restrict__ theta_tab,
                              const float* __restrict__ w_tab,
                              const float* __restrict__ score_scale,
                              const float* __restrict__ tanh_scale,
                              const float* __restrict__ slopes_sp,
                              const float* __restrict__ cpre,
                              const float* __restrict__ gatelin,
                              const float* __restrict__ gate_b,
                              const float* __restrict__ ns,
                              _Float16* __restrict__ asp) {
  const int c = blockIdx.x, k = blockIdx.y, b = blockIdx.z;
  const int tid = threadIdx.x;
  const int m = tid & 3, h = tid >> 2;
  const int chk = k * H_ + h;
  const int chs = 768 + k;
  size_t base = (((size_t)b * K_ + k) * NC_ + c) * 513;
  float den = cpre[base];
  float sre = cpre[base + 1 + h * 4 + m];
  float sim = cpre[base + 1 + 256 + h * 4 + m];
  const float theta_v = theta_tab[chk * M_ + m];
  const float w = w_tab[chk * M_ + m];
  const float ts = tanh_scale[k], ss = score_scale[k], slope = slopes_sp[k];
  const float nsv = ns[chk];
  const float gb = gate_b[k];
  const int kq = k >> 1;   // NREP = 2
  float ckv[4], cks[4];
#pragma unroll
  for (int ww = 0; ww < 4; ++ww) { ckv[ww] = ck[ww * ZC_ + chk]; cks[ww] = ck[ww * ZC_ + chs]; }
  const int l0 = c * LC_;
  float zk3 = 0.f, zk2 = 0.f, zk1 = 0.f, zs3 = 0.f, zs2 = 0.f, zs1 = 0.f;
#pragma unroll
  for (int p = 0; p < 3; ++p) {
    int lp = l0 - 3 + p;
    if (lp >= 0) {
      size_t tp = (size_t)b * L_ + lp;
      float zk = zp[tp * ZC_ + chk], zs = zp[tp * ZC_ + chs];
      if (p == 0) { zk3 = zk; zs3 = zs; }
      else if (p == 1) { zk2 = zk; zs2 = zs; }
      else { zk1 = zk; zs1 = zs; }
    }
  }
  const int qidx = ((kq * H_ + h) * M_ + m) * 2;
  for (int ll = 0; ll < LC_; ++ll) {
    int l = l0 + ll;
    size_t t = (size_t)b * L_ + l;
    float zk0 = zp[t * ZC_ + chk];
    float zs0 = zp[t * ZC_ + chs];
    float kv = zk3 * ckv[0] + zk2 * ckv[1] + zk1 * ckv[2] + zk0 * ckv[3];
    float sraw = zs3 * cks[0] + zs2 * cks[1] + zs1 * cks[2] + zs0 * cks[3];
    zk3 = zk2; zk2 = zk1; zk1 = zk0;
    zs3 = zs2; zs2 = zs1; zs1 = zs0;
    float lp = fminf(fmaxf(ss * sraw, -20.f), 20.f);
    float pw = __expf(lp - slope * (float)(L_ - 1 - l));
    float ph = fast_tanh(ts * kv) * theta_v;
    float kvp = kv * pw;
    sre += kvp * __cosf(ph);
    sim += kvp * __sinf(ph);
    den += pw;
    float inv = 1.f / fmaxf(den, 1e-4f);
    float s_re = sre * inv, s_im = sim * inv;
    size_t qb = t * QST_ + qidx;
    float qr = (float)qh[qb], qi = (float)qh[qb + 1];
    float tr = (s_re * qr + s_im * qi) * w;
    float ti = (s_im * qr - s_re * qi) * w;
    tr += __shfl_xor(tr, 1); tr += __shfl_xor(tr, 2);
    ti += __shfl_xor(ti, 1); ti += __shfl_xor(ti, 2);
    if (m == 0) {
      float g = 1.f / (1.f + __expf(-(gatelin[t * K_ + k] + gb))) * nsv;
      size_t ab = ((size_t)k * NTOK_ + t) * 128;
      asp[ab + h] = (_Float16)(tr * g);
      asp[ab + 64 + h] = (_Float16)(ti * g);
    }
  }
}

// ---------------------------------------------------------------------------
extern "C" void kernel_launch(void* const* d_in, const int* in_sizes, int n_in,
                              void* d_out, int out_size, void* d_ws, size_t ws_size,
                              hipStream_t stream) {
  const float* x            = (const float*)d_in[0];
  const float* W_mem        = (const float*)d_in[1];
  const float* conv_k       = (const float*)d_in[2];
  const float* W_q          = (const float*)d_in[3];
  const float* theta_d_raw  = (const float*)d_in[4];
  const float* decay_slopes = (const float*)d_in[5];
  const float* score_scale  = (const float*)d_in[6];
  const float* tanh_scale   = (const float*)d_in[7];
  const float* W_re         = (const float*)d_in[8];
  const float* W_im         = (const float*)d_in[9];
  const float* norm_scale   = (const float*)d_in[10];
  const float* gate_W       = (const float*)d_in[11];
  const float* gate_b       = (const float*)d_in[12];
  const float* skip_down_W  = (const float*)d_in[13];
  const float* skip_up_W    = (const float*)d_in[14];
  const float* highway_scale= (const float*)d_in[15];
  const float* out_W        = (const float*)d_in[16];
  float* out = (float*)d_out;
  float* ws = (float*)d_ws;

  // ---- f32 region ----
  float* theta_tab = ws;                                  // 3072
  float* w_tab     = theta_tab + 3072;                    // 3072
  float* slopes_sp = w_tab + 3072;                        // 16
  float* z_pre     = slopes_sp + 16;                      // 3,194,880
  float* gatelin   = z_pre + (size_t)NTOK_ * ZC_;         // 49,152
  float* csums     = gatelin + (size_t)NTOK_ * K_;        // 787,968
  float* cpre      = csums + (size_t)B_ * K_ * NC_ * 513; // 787,968
  _Float16* q_h    = (_Float16*)(cpre + (size_t)B_ * K_ * NC_ * 513); // 4096x3072
  _Float16* y_h    = q_h + (size_t)NTOK_ * QST_;          // 4096x2304
  float* f32_end   = (float*)(y_h + (size_t)NTOK_ * 2304);

  // ---- fp16 region ----
  _Float16* fp = (_Float16*)f32_end;
  _Float16* x_h    = fp;                fp += (size_t)NTOK_ * D_;
  _Float16* xpb_h  = fp;                fp += (size_t)XPN_ * 768;   // merged proj B (4352 rows)
  _Float16* outw_h = fp;                fp += (size_t)768 * 2304;
  _Float16* asp2_h = fp;                fp += (size_t)K_ * NTOK_ * 128;
  _Float16* bsp_h  = fp;                fp += (size_t)K_ * 384 * 320;
  _Float16* lat_h  = fp;                fp += (size_t)NTOK_ * 192;

  // fused prologue: precomp + all weight conversions (incl gate_W) + out-zero + x->fp16
  prep_kernel<<<18651, 256, 0, stream>>>(x, W_mem, W_q, skip_down_W, out_W, W_re, W_im,
                                         skip_up_W, highway_scale, gate_W,
                                         theta_d_raw, decay_slopes,
                                         out, x_h, xpb_h, outw_h, bsp_h,
                                         theta_tab, w_tab, slopes_sp);

  // merged x-projection (256-tile 8-phase): q + lat + gate + z_pre in ONE dispatch
  xproj256_kernel<<<272, 512, 0, stream>>>(x_h, xpb_h, z_pre, lat_h, q_h, gatelin);

  // chunked scan (f32) with fused causal conv
  pass_a_kernel<<<dim3(NC_, K_, B_), 256, 0, stream>>>(z_pre, conv_k, theta_tab, score_scale,
                                                       tanh_scale, slopes_sp, csums);
  pass_b_kernel<<<dim3(9, B_ * K_), 64, 0, stream>>>(csums, cpre);
  pass_c_kernel<<<dim3(NC_, K_, B_), 256, 0, stream>>>(z_pre, conv_k, q_h, theta_tab, w_tab,
                                                       score_scale, tanh_scale, slopes_sp, cpre,
                                                       gatelin, gate_b, norm_scale, asp2_h);

  // batched spec GEMM (A = [asp2 per-k | lat_h shared], hs folded into bsp)
  // with fused SiLU -> y_h fp16; XCD-chunked 1D grid (3x32x12 blocks)
  mfma_gemm_kernel<0, 1><<<1152, 256, 0, stream>>>(asp2_h, bsp_h, nullptr,
                                                   320, 384,
                                                   (long)NTOK_ * 128, 384L * 320, 0,
                                                   lat_h, y_h, 0, 0, 0);
  // out += y @ out_W  (split-K=4, atomic, XCD-swizzled 1D grid)
  mfma_gemm_kernel<1, 0><<<768, 256, 0, stream>>>(y_h, outw_h, out,
                                                  2304, 768, 0, 0, 0,
                                                  nullptr, nullptr, 6, 32, 4);
}

// Round 3
// 297.473 us; speedup vs baseline: 1.0892x; 1.0892x over previous
//
#include <hip/hip_runtime.h>
#include <math.h>

#define B_    2
#define L_    2048
#define D_    768
#define K_    12
#define KQ_   6
#define M_    4
#define H_    64
#define ZC_   780      // MEM + K
#define NTOK_ 4096     // B*L
#define NC_   64       // scan chunks per batch
#define LC_   32       // chunk length (L/NC)
#define QST_  3072     // q fp16 row stride
#define XPN_  4096     // merged projection N (exactly 16 x 256 tiles -> no grid tail)
#define ZOFF_ 3276     // z_pre column base in xpb

typedef __attribute__((ext_vector_type(8))) _Float16 half8;
typedef __attribute__((ext_vector_type(4))) float f32x4;

__device__ __forceinline__ float softplus_f(float x) {
  return (x > 20.f) ? x : log1pf(expf(x));
}

__device__ __forceinline__ float fast_tanh(float x) {
  float xx = fminf(fmaxf(x, -10.f), 10.f);
  float e = __expf(2.f * xx);
  return (e - 1.f) / (e + 1.f);
}

// async global->LDS 16B per lane (dest = wave-uniform base + lane*16)
__device__ __forceinline__ void async16(const _Float16* g, _Float16* l) {
  __builtin_amdgcn_global_load_lds(
      (const __attribute__((address_space(1))) unsigned int*)g,
      (__attribute__((address_space(3))) unsigned int*)l, 16, 0, 0);
}

// val/gate 16-interleave permutation for spec-B columns
__device__ __forceinline__ int permcol(int n) {
  int isg = (n >= 192) ? 1 : 0;
  int j = n - 192 * isg;
  return (j >> 4) * 32 + (isg << 4) + (j & 15);
}

#define FENCE() asm volatile("" ::: "memory")

// ---------------------------------------------------------------------------
// Transpose+convert body; optional perm + scale. Nst = store-row limit
// (prevents pad-zero stores from racing into a neighboring region).
// ---------------------------------------------------------------------------
__device__ __forceinline__ void cvt_t_body(float (*tile)[33], int bx, int by, int kz,
                                           const float* src, long sKs, int srs,
                                           _Float16* dh, long dKs, int dst, int doff,
                                           int R, int Nact, int Nst, bool perm, float scale) {
  const float* s = src + (size_t)kz * sKs;
  _Float16* dhh = dh + (size_t)kz * dKs;
  const int kb = bx * 32;
  const int nb = by * 32;
  const int tx = threadIdx.x & 31, ty = threadIdx.x >> 5;
  for (int i = ty; i < 32; i += 8) {
    int kk = kb + i, n = nb + tx;
    tile[i][tx] = (kk < R && n < Nact) ? s[(size_t)kk * srs + n] : 0.f;
  }
  __syncthreads();
  for (int i = ty; i < 32; i += 8) {
    int n = nb + i, kk = kb + tx;
    if (kk < R && n < Nst) {
      float v = tile[tx][i] * scale;
      int dn = perm ? permcol(n) : n;
      dhh[(size_t)dn * dst + doff + kk] = (_Float16)v;
    }
  }
}

// ---------------------------------------------------------------------------
// Fused prologue, ONE dispatch:
//   blocks [0,3):          precomp (theta/w tables, slopes)
//   blocks [3,6363):       all weight conversions (incl. gate_W -> xpb cols)
//   blocks [6363,18651):   out zero-fill + x f32->fp16
// xpb layout (rows x 768): [W_q^T 0:3072 | skd^T 3072:3264 | gate^T 3264:3276 |
//                           W_mem^T 3276:4056 | dead 4056:4096]
// ---------------------------------------------------------------------------
__global__ __launch_bounds__(256)
void prep_kernel(const float* __restrict__ x,
                 const float* __restrict__ W_mem, const float* __restrict__ W_q,
                 const float* __restrict__ skip_down_W, const float* __restrict__ out_W,
                 const float* __restrict__ W_re, const float* __restrict__ W_im,
                 const float* __restrict__ skip_up_W, const float* __restrict__ hs,
                 const float* __restrict__ gate_W,
                 const float* __restrict__ theta_d_raw, const float* __restrict__ decay,
                 float* __restrict__ out, _Float16* __restrict__ x_h,
                 _Float16* __restrict__ xpb_h, _Float16* __restrict__ outw_h,
                 _Float16* __restrict__ bsp_h,
                 float* __restrict__ theta_tab, float* __restrict__ w_tab,
                 float* __restrict__ slopes_sp) {
  __shared__ float tile[32][33];
  int b = blockIdx.x;
  if (b < 3) {
    int idx = b * 256 + threadIdx.x;
    if (idx < K_) slopes_sp[idx] = softplus_f(decay[idx]);
    if (idx >= K_ * H_) return;
    float td[M_], ta[M_];
#pragma unroll
    for (int m = 0; m < M_; ++m) td[m] = softplus_f(theta_d_raw[idx * M_ + m]) + 1e-4f;
    ta[0] = td[0];
#pragma unroll
    for (int m = 1; m < M_; ++m) ta[m] = ta[m - 1] + td[m];
    float total = ta[M_ - 1];
    float rs = 2.999f / total;
#pragma unroll
    for (int m = 0; m < M_; ++m) theta_tab[idx * M_ + m] = 0.001f + ta[m] * rs;
    float d0 = (ta[1] - ta[0]) * rs;
    float d1 = (ta[2] - ta[1]) * rs;
    float d2 = (ta[3] - ta[2]) * rs;
    w_tab[idx * M_ + 0] = 0.5f * d0;
    w_tab[idx * M_ + 1] = 0.5f * (d0 + d1);
    w_tab[idx * M_ + 2] = 0.5f * (d1 + d2);
    w_tab[idx * M_ + 3] = 0.5f * d2;
    return;
  }
  b -= 3;
  if (b < 6360) {
    if (b < 672) {           // W_mem -> xpb rows [3276,4056), 24x28
      cvt_t_body(tile, b % 24, b / 24, 0, W_mem, 0, ZC_, xpb_h + (size_t)ZOFF_ * 768,
                 0, 768, 0, 768, ZC_, ZC_, false, 1.f);
      return;
    }
    b -= 672;
    if (b < 2304) {          // W_q -> xpb rows [0,3072), 24x96
      cvt_t_body(tile, b % 24, b / 24, 0, W_q, 0, 3072, xpb_h, 0, 768, 0, 768,
                 3072, 3072, false, 1.f);
      return;
    }
    b -= 2304;
    if (b < 192) {           // skip_down -> xpb rows [3072,3264), 24x8
      cvt_t_body(tile, b % 24, b / 24, 0, skip_down_W, 0, 192, xpb_h + (size_t)3072 * 768,
                 0, 768, 0, 768, 192, 192, false, 1.f);
      return;
    }
    b -= 192;
    if (b < 1728) {          // out_W -> outw, 72x24
      cvt_t_body(tile, b % 72, b / 72, 0, out_W, 0, 768, outw_h, 0, 2304, 0, 2304,
                 768, 768, false, 1.f);
      return;
    }
    b -= 1728;
    if (b < 288) {           // W_re -> bsp[k][perm(n)][0:64], 2x12x12
      cvt_t_body(tile, b % 2, (b / 2) % 12, b / 24, W_re, 64L * 384, 384, bsp_h,
                 384L * 320, 320, 0, 64, 384, 384, true, 1.f);
      return;
    }
    b -= 288;
    if (b < 288) {           // W_im -> bsp[k][perm(n)][64:128]
      cvt_t_body(tile, b % 2, (b / 2) % 12, b / 24, W_im, 64L * 384, 384, bsp_h,
                 384L * 320, 320, 64, 64, 384, 384, true, 1.f);
      return;
    }
    b -= 288;
    if (b < 864) {           // skip_up slice -> bsp[k][perm(n)][128:320] scaled by hs[k]
      int kz = b / 72;
      cvt_t_body(tile, b % 6, (b / 6) % 12, kz, skip_up_W, 384, 4608, bsp_h,
                 384L * 320, 320, 128, 192, 384, 384, true, hs[kz]);
      return;
    }
    b -= 864;
    // gate_W (768x12) -> xpb rows [3264,3276), 24 blocks; store-limited to 12 rows
    cvt_t_body(tile, b, 0, 0, gate_W, 0, K_, xpb_h + (size_t)3264 * 768,
               0, 768, 0, 768, K_, K_, false, 1.f);
    return;
  }
  b -= 6360;
  size_t i = (size_t)b * 256 + threadIdx.x;
  if (i < (size_t)NTOK_ * D_) {
    out[i] = 0.f;                    // zero split-K atomic target
    x_h[i] = (_Float16)x[i];         // x -> fp16
  }
}

// ---------------------------------------------------------------------------
// 256x256-tile 8-phase deep-pipelined MFMA GEMM for the merged x-projection.
// M=4096, N=4096, K=768, BK=64, 12 K-tiles, 512 threads (8 waves 2Mx4N),
// 128 KiB dbuf LDS. LDS layout: per K-tile half, TWO [128][32] subtiles
// (row = 64B = 16 banks, proven-0-conflict swizzle from the 2-phase kernel).
// Grid = 16x16 = 256 blocks = exactly 1 block/CU: no tail round.
// Per K-tile: 4 phases x 16 MFMA/wave; register subtiles read one phase ahead;
// half-tiles staged with 3-4 phase flight; ONE vmcnt drain per K-tile placed
// BEFORE a barrier (cross-wave DMA visibility).
// Epilogue: col<3072 -> QH fp16; [3072,3264) -> YH fp16 (lat); [3264,3276) ->
// GL f32 (gate linear); [3276,4056) -> C f32 (z_pre); else dead (discarded).
// ---------------------------------------------------------------------------
__global__ __launch_bounds__(512, 2)
void xproj256_kernel(const _Float16* __restrict__ Ah, const _Float16* __restrict__ Bh,
                     float* __restrict__ C, _Float16* __restrict__ YH,
                     _Float16* __restrict__ QH, float* __restrict__ GL) {
  // [dbuf][Mhalf/Nhalf][Khalf][row][col32]
  __shared__ __align__(16) _Float16 sA[2][2][2][128][32];
  __shared__ __align__(16) _Float16 sB[2][2][2][128][32];

  // bijective XCD chunking: 256 blocks = 8 xcd x 32; xcd owns 2 by-rows x 16 bx
  const int bid = blockIdx.x;
  const int xcd = bid & 7, s = bid >> 3;        // s in [0,32)
  const int by = xcd * 2 + (s & 1);             // 0..15
  const int bx = s >> 1;                        // 0..15
  const int bm0 = by * 256, bn0 = bx * 256;

  const int tid = threadIdx.x;
  const int lane = tid & 63;
  const int wave = tid >> 6;
  const int m16 = lane & 15, quad = lane >> 4;
  const int wr = wave >> 2;          // 0..1 A-half
  const int wc = wave & 3;           // 0..3 B col group (64 cols)
  const int bhalf = wc >> 1;         // B LDS half
  const int brow0 = (wc & 1) * 64;   // row base within B half

  f32x4 acc[8][4];
#pragma unroll
  for (int i = 0; i < 8; ++i)
#pragma unroll
    for (int j = 0; j < 4; ++j) acc[i][j] = (f32x4){0.f, 0.f, 0.f, 0.f};

  // staging geometry: thread covers 16B block lb of row sr, one async16 per K-half
  const int sr = tid >> 2;           // 0..127
  const int lb = tid & 3;            // 16B block within 32-half subtile row
  const int ssw = (sr >> 1) & 3;     // row swizzle term

  auto stageA = [&](int t, int h) {
    const int bb = t & 1;
    const _Float16* g = Ah + (size_t)(bm0 + h * 128 + sr) * 768 + t * 64
                        + ((lb ^ ssw) << 3);
    async16(g,      &sA[bb][h][0][0][0] + (size_t)tid * 8);
    async16(g + 32, &sA[bb][h][1][0][0] + (size_t)tid * 8);
  };
  auto stageB = [&](int t, int h) {
    const int bb = t & 1;
    const _Float16* g = Bh + (size_t)(bn0 + h * 128 + sr) * 768 + t * 64
                        + ((lb ^ ssw) << 3);
    async16(g,      &sB[bb][h][0][0][0] + (size_t)tid * 8);
    async16(g + 32, &sB[bb][h][1][0][0] + (size_t)tid * 8);
  };

  auto ldA = [&](int bb, int r, int kk) -> half8 {
    return *(const half8*)&sA[bb][wr][kk][r][(quad ^ ((r >> 1) & 3)) << 3];
  };
  auto ldB = [&](int bb, int r, int kk) -> half8 {
    return *(const half8*)&sB[bb][bhalf][kk][r][(quad ^ ((r >> 1) & 3)) << 3];
  };

  half8 aLo[8], aHi[8], bLo[4], bHi[4];

  // ---- prologue: stage K-tiles 0 and 1 (B before A, matching steady order)
  stageB(0, 0); stageB(0, 1); stageA(0, 0); stageA(0, 1);
  stageB(1, 0); stageB(1, 1); stageA(1, 0); stageA(1, 1);
  __builtin_amdgcn_s_waitcnt(0x0F78);   // vmcnt(8): K-tile 0 landed
  FENCE(); __builtin_amdgcn_s_barrier(); FENCE();
  // pre-reads for phase (0,0): aLo(0), bLo(0)
#pragma unroll
  for (int m = 0; m < 4; ++m)
#pragma unroll
    for (int kk = 0; kk < 2; ++kk) aLo[m * 2 + kk] = ldA(0, m * 16 + m16, kk);
#pragma unroll
  for (int n = 0; n < 2; ++n)
#pragma unroll
    for (int kk = 0; kk < 2; ++kk) bLo[n * 2 + kk] = ldB(0, brow0 + n * 16 + m16, kk);

  for (int t = 0; t < 12; ++t) {
    const int bb = t & 1;
    const int nb = bb ^ 1;
    // ---------- phase 0: read bHi(t); MFMA lo-lo ----------
#pragma unroll
    for (int n = 0; n < 2; ++n)
#pragma unroll
      for (int kk = 0; kk < 2; ++kk)
        bHi[n * 2 + kk] = ldB(bb, brow0 + (n + 2) * 16 + m16, kk);
    FENCE(); __builtin_amdgcn_s_barrier(); FENCE();
    __builtin_amdgcn_s_setprio(1);
#pragma unroll
    for (int m = 0; m < 4; ++m)
#pragma unroll
      for (int n = 0; n < 2; ++n)
#pragma unroll
        for (int kk = 0; kk < 2; ++kk)
          acc[m][n] = __builtin_amdgcn_mfma_f32_16x16x32_f16(aLo[m * 2 + kk], bLo[n * 2 + kk],
                                                             acc[m][n], 0, 0, 0);
    __builtin_amdgcn_s_setprio(0);
    FENCE(); __builtin_amdgcn_s_barrier(); FENCE();
    // ---------- phase 1: read aHi(t); MFMA lo-hi; drain vmcnt (once/K-tile) ----------
#pragma unroll
    for (int m = 0; m < 4; ++m)
#pragma unroll
      for (int kk = 0; kk < 2; ++kk)
        aHi[m * 2 + kk] = ldA(bb, 64 + m * 16 + m16, kk);
    FENCE(); __builtin_amdgcn_s_barrier(); FENCE();
    __builtin_amdgcn_s_setprio(1);
#pragma unroll
    for (int m = 0; m < 4; ++m)
#pragma unroll
      for (int n = 2; n < 4; ++n)
#pragma unroll
        for (int kk = 0; kk < 2; ++kk)
          acc[m][n] = __builtin_amdgcn_mfma_f32_16x16x32_f16(aLo[m * 2 + kk], bHi[(n - 2) * 2 + kk],
                                                             acc[m][n], 0, 0, 0);
    __builtin_amdgcn_s_setprio(0);
    __builtin_amdgcn_s_waitcnt(0x0F70);   // vmcnt(0): K-tile t+1 landed (issued 4+ phases ago)
    FENCE(); __builtin_amdgcn_s_barrier(); FENCE();
    // ---------- phase 2: read aLo(t+1); stage B(t+2); MFMA hi-lo ----------
    if (t < 11) {
#pragma unroll
      for (int m = 0; m < 4; ++m)
#pragma unroll
        for (int kk = 0; kk < 2; ++kk)
          aLo[m * 2 + kk] = ldA(nb, m * 16 + m16, kk);
    }
    if (t < 10) { stageB(t + 2, 0); stageB(t + 2, 1); }
    FENCE(); __builtin_amdgcn_s_barrier(); FENCE();
    __builtin_amdgcn_s_setprio(1);
#pragma unroll
    for (int m = 0; m < 4; ++m)
#pragma unroll
      for (int n = 0; n < 2; ++n)
#pragma unroll
        for (int kk = 0; kk < 2; ++kk)
          acc[m + 4][n] = __builtin_amdgcn_mfma_f32_16x16x32_f16(aHi[m * 2 + kk], bLo[n * 2 + kk],
                                                                 acc[m + 4][n], 0, 0, 0);
    __builtin_amdgcn_s_setprio(0);
    FENCE(); __builtin_amdgcn_s_barrier(); FENCE();
    // ---------- phase 3: read bLo(t+1); stage A(t+2); MFMA hi-hi ----------
    if (t < 11) {
#pragma unroll
      for (int n = 0; n < 2; ++n)
#pragma unroll
        for (int kk = 0; kk < 2; ++kk)
          bLo[n * 2 + kk] = ldB(nb, brow0 + n * 16 + m16, kk);
    }
    if (t < 10) { stageA(t + 2, 0); stageA(t + 2, 1); }
    FENCE(); __builtin_amdgcn_s_barrier(); FENCE();
    __builtin_amdgcn_s_setprio(1);
#pragma unroll
    for (int m = 0; m < 4; ++m)
#pragma unroll
      for (int n = 2; n < 4; ++n)
#pragma unroll
        for (int kk = 0; kk < 2; ++kk)
          acc[m + 4][n] = __builtin_amdgcn_mfma_f32_16x16x32_f16(aHi[m * 2 + kk], bHi[(n - 2) * 2 + kk],
                                                                 acc[m + 4][n], 0, 0, 0);
    __builtin_amdgcn_s_setprio(0);
    FENCE(); __builtin_amdgcn_s_barrier(); FENCE();
  }

  // ---- epilogue (C/D layout: col=lane&15, row=quad*4+reg) ----
#pragma unroll
  for (int m = 0; m < 8; ++m) {
    const int row0 = bm0 + wr * 128 + m * 16 + quad * 4;
#pragma unroll
    for (int n = 0; n < 4; ++n) {
      const int col = bn0 + wc * 64 + n * 16 + m16;
      if (col < 3072) {
#pragma unroll
        for (int r = 0; r < 4; ++r)
          QH[(size_t)(row0 + r) * QST_ + col] = (_Float16)acc[m][n][r];
      } else if (col < 3264) {
        const int jj = col - 3072;
#pragma unroll
        for (int r = 0; r < 4; ++r)
          YH[(size_t)(row0 + r) * 192 + jj] = (_Float16)acc[m][n][r];
      } else if (col < 3276) {
        const int kk = col - 3264;
#pragma unroll
        for (int r = 0; r < 4; ++r)
          GL[(size_t)(row0 + r) * K_ + kk] = acc[m][n][r];
      } else if (col < 3276 + ZC_) {
        const int wz = col - ZOFF_;
#pragma unroll
        for (int r = 0; r < 4; ++r)
          C[(size_t)(row0 + r) * ZC_ + wz] = acc[m][n][r];
      }
    }
  }
}

// ---------------------------------------------------------------------------
// MFMA fp16 GEMM (128x128, 2-phase): kept for spec GEMM and out GEMM.
// EPI=0: f32 store. ATOMIC=1: 1D XCD-swizzled grid (gx,gy,nsplit), atomicAdd.
// EPI=1: spec GEMM: A from split source; fused val/gate SiLU -> YH; XCD-chunked.
// ---------------------------------------------------------------------------
template <int ATOMIC, int EPI>
__global__ __launch_bounds__(256)
void mfma_gemm_kernel(const _Float16* __restrict__ Ah, const _Float16* __restrict__ Bh,
                      float* __restrict__ C,
                      int Kd, int Nact,
                      long strideA, long strideB, long strideC,
                      const _Float16* __restrict__ A2, _Float16* __restrict__ YH,
                      int gx, int gy, int nsplit) {
  __shared__ __align__(16) _Float16 sA[2][128 * 32];
  __shared__ __align__(16) _Float16 sB[2][128 * 32];
  int bx, by, kz, kbeg, kend;
  if (ATOMIC) {
    int bid = blockIdx.x;
    int xcd = bid & 7, s = bid >> 3;
    bx = s % gx;
    int yz = s / gx;
    int p = xcd + 8 * yz;
    by = p % gy;
    int zz = p / gy;
    kz = 0;
    int len = Kd / nsplit;
    kbeg = zz * len;
    kend = kbeg + len;
  } else if (EPI == 1) {
    // 1152 blocks = 3bx x 32by x 12kz; XCD x owns by in [4x,4x+4) for all kz
    int bid = blockIdx.x;
    int xcd = bid & 7, s = bid >> 3;        // s in [0,144)
    kz = s / 12;
    int w = s % 12;
    bx = w % 3;
    by = (xcd << 2) + w / 3;
    kbeg = 0; kend = Kd;
  } else {
    bx = blockIdx.x; by = blockIdx.y; kz = blockIdx.z;
    kbeg = 0; kend = Kd;
  }
  const _Float16* A0 = Ah + (size_t)kz * strideA;
  const _Float16* B0 = Bh + (size_t)kz * strideB;
  float* Cb = C + (size_t)kz * strideC;
  const int bm0 = by * 128;
  const int bn0 = bx * 128;
  const int tid = threadIdx.x;
  const int wave = tid >> 6, lane = tid & 63;
  const int m16 = lane & 15, quad = lane >> 4;
  const int wr = (wave & 1) * 64, wc = (wave >> 1) * 64;

  f32x4 acc[4][4];
#pragma unroll
  for (int i = 0; i < 4; ++i)
#pragma unroll
    for (int j = 0; j < 4; ++j) acc[i][j] = (f32x4){0.f, 0.f, 0.f, 0.f};

  const int lin = tid * 8;
  const int lrow = lin >> 5;
  const int lblk = (lin >> 3) & 3;
  const int csw = ((lblk ^ ((lrow >> 1) & 3)) << 3);

  auto stage = [&](int k0, int kb) {
    if constexpr (EPI == 1) {
      if (k0 < 128) {
        const _Float16* gA = A0 + (size_t)(bm0 + lrow) * 128 + (k0 + csw);
        async16(gA, &sA[kb][lin]);
        async16(gA + (size_t)64 * 128, &sA[kb][lin + 2048]);
      } else {
        const _Float16* gA = A2 + (size_t)(bm0 + lrow) * 192 + (k0 - 128 + csw);
        async16(gA, &sA[kb][lin]);
        async16(gA + (size_t)64 * 192, &sA[kb][lin + 2048]);
      }
    } else {
      const _Float16* gA = A0 + (size_t)(bm0 + lrow) * Kd + (k0 + csw);
      async16(gA, &sA[kb][lin]);
      async16(gA + (size_t)64 * Kd, &sA[kb][lin + 2048]);
    }
    const _Float16* gB = B0 + (size_t)(bn0 + lrow) * Kd + (k0 + csw);
    async16(gB, &sB[kb][lin]);
    async16(gB + (size_t)64 * Kd, &sB[kb][lin + 2048]);
  };

  const int niter = (kend - kbeg) / 32;
  stage(kbeg, 0);
  if (niter > 1) stage(kbeg + 32, 1);

  for (int it = 0; it < niter; ++it) {
    if (it == niter - 1)
      __builtin_amdgcn_s_waitcnt(0x0F70);   // vmcnt(0)
    else
      __builtin_amdgcn_s_waitcnt(0x0F74);   // vmcnt(4)
    __builtin_amdgcn_s_barrier();
    asm volatile("" ::: "memory");
    const int kb = it & 1;
    half8 a0[4], b0[4];
#pragma unroll
    for (int i = 0; i < 4; ++i) {
      const int rA = wr + i * 16 + m16;
      a0[i] = *(const half8*)&sA[kb][rA * 32 + ((quad ^ ((rA >> 1) & 3)) << 3)];
    }
#pragma unroll
    for (int j = 0; j < 4; ++j) {
      const int rB = wc + j * 16 + m16;
      b0[j] = *(const half8*)&sB[kb][rB * 32 + ((quad ^ ((rB >> 1) & 3)) << 3)];
    }
#pragma unroll
    for (int i = 0; i < 4; ++i)
#pragma unroll
      for (int j = 0; j < 4; ++j)
        acc[i][j] = __builtin_amdgcn_mfma_f32_16x16x32_f16(a0[i], b0[j], acc[i][j], 0, 0, 0);
    asm volatile("" ::: "memory");
    __builtin_amdgcn_s_barrier();
    asm volatile("" ::: "memory");
    if (it + 2 < niter) stage(kbeg + (it + 2) * 32, kb);
  }

  if constexpr (EPI == 1) {
#pragma unroll
    for (int i = 0; i < 4; ++i) {
      const int row0 = bm0 + wr + i * 16 + quad * 4;
#pragma unroll
      for (int j = 0; j < 4; j += 2) {
        const int colv = bn0 + wc + j * 16 + m16;
        const int jout = (colv >> 5) * 16 + m16;
#pragma unroll
        for (int r = 0; r < 4; ++r) {
          float val = acc[i][j][r];
          float g = acc[i][j + 1][r];
          float sg = g / (1.f + __expf(-g));
          YH[(size_t)(row0 + r) * 2304 + kz * 192 + jout] = (_Float16)(val * sg);
        }
      }
    }
  } else {
#pragma unroll
    for (int i = 0; i < 4; ++i) {
      const int row0 = bm0 + wr + i * 16 + quad * 4;
#pragma unroll
      for (int j = 0; j < 4; ++j) {
        const int col = bn0 + wc + j * 16 + m16;
        if (col < Nact) {
#pragma unroll
          for (int r = 0; r < 4; ++r) {
            if (ATOMIC)
              atomicAdd(&Cb[(size_t)(row0 + r) * Nact + col], acc[i][j][r]);
            else
              Cb[(size_t)(row0 + r) * Nact + col] = acc[i][j][r];
          }
        }
      }
    }
  }
}

// ---------------------------------------------------------------------------
// Scan pass A with fused causal conv (sliding 4-tap window over z_pre)
// ---------------------------------------------------------------------------
__global__ void pass_a_kernel(const float* __restrict__ zp,
                              const float* __restrict__ ck,
                              const float* __restrict__ theta_tab,
                              const float* __restrict__ score_scale,
                              const float* __restrict__ tanh_scale,
                              const float* __restrict__ slopes_sp,
                              float* __restrict__ csums) {
  const int c = blockIdx.x, k = blockIdx.y, b = blockIdx.z;
  const int tid = threadIdx.x;
  const int m = tid & 3, h = tid >> 2;
  const int chk = k * H_ + h;
  const int chs = 768 + k;
  const float theta_v = theta_tab[chk * M_ + m];
  const float ts = tanh_scale[k], ss = score_scale[k], slope = slopes_sp[k];
  float ckv[4], cks[4];
#pragma unroll
  for (int w = 0; w < 4; ++w) { ckv[w] = ck[w * ZC_ + chk]; cks[w] = ck[w * ZC_ + chs]; }
  const int l0 = c * LC_;
  float zk3 = 0.f, zk2 = 0.f, zk1 = 0.f, zs3 = 0.f, zs2 = 0.f, zs1 = 0.f;
#pragma unroll
  for (int p = 0; p < 3; ++p) {
    int lp = l0 - 3 + p;
    if (lp >= 0) {
      size_t tp = (size_t)b * L_ + lp;
      float zk = zp[tp * ZC_ + chk], zs = zp[tp * ZC_ + chs];
      if (p == 0) { zk3 = zk; zs3 = zs; }
      else if (p == 1) { zk2 = zk; zs2 = zs; }
      else { zk1 = zk; zs1 = zs; }
    }
  }
  float sre = 0.f, sim = 0.f, dacc = 0.f;
  for (int ll = 0; ll < LC_; ++ll) {
    int l = l0 + ll;
    size_t t = (size_t)b * L_ + l;
    float zk0 = zp[t * ZC_ + chk];
    float zs0 = zp[t * ZC_ + chs];
    float kv = zk3 * ckv[0] + zk2 * ckv[1] + zk1 * ckv[2] + zk0 * ckv[3];
    float sraw = zs3 * cks[0] + zs2 * cks[1] + zs1 * cks[2] + zs0 * cks[3];
    zk3 = zk2; zk2 = zk1; zk1 = zk0;
    zs3 = zs2; zs2 = zs1; zs1 = zs0;
    float lp = fminf(fmaxf(ss * sraw, -20.f), 20.f);
    float pw = __expf(lp - slope * (float)(L_ - 1 - l));
    float ph = fast_tanh(ts * kv) * theta_v;
    float kvp = kv * pw;
    sre += kvp * __cosf(ph);
    sim += kvp * __sinf(ph);
    dacc += pw;
  }
  size_t base = (((size_t)b * K_ + k) * NC_ + c) * 513;
  if (tid == 0) csums[base] = dacc;
  csums[base + 1 + h * 4 + m] = sre;
  csums[base + 1 + 256 + h * 4 + m] = sim;
}

// ---------------------------------------------------------------------------
__global__ void pass_b_kernel(const float* __restrict__ csums,
                              float* __restrict__ cpre) {
  int bk = blockIdx.y;
  int comp = blockIdx.x * 64 + threadIdx.x;
  if (comp >= 513) return;
  float run = 0.f;
  size_t base = (size_t)bk * NC_ * 513 + comp;
  for (int c = 0; c < NC_; ++c) {
    cpre[base + (size_t)c * 513] = run;
    run += csums[base + (size_t)c * 513];
  }
}

// ---------------------------------------------------------------------------
// Scan pass C: fused conv replay, contract with fp16 q, apply ns*gate,
// write fp16 into asp2[k][t][0:128] (128-stride)
// ---------------------------------------------------------------------------
__global__ void pass_c_kernel(const float* __restrict__ zp,
                              const float* __restrict__ ck,
                              const _Float16* __restrict__ qh,
                              const float* __restrict__ theta_tab,
                              const float* __restrict__ w_tab,
                              const float* __restrict__ score_scale,
                              const float* __restrict__ tanh_scale,
                              const float* __restrict__ slopes_sp,
                              const float* __restrict__ cpre,
                              const float* __restrict__ gatelin,
                              const float* __restrict__ gate_b,
                              const float* __restrict__ ns,
                              _Float16* __restrict__ asp) {
  const int c = blockIdx.x, k = blockIdx.y, b = blockIdx.z;
  const int tid = threadIdx.x;
  const int m = tid & 3, h = tid >> 2;
  const int chk = k * H_ + h;
  const int chs = 768 + k;
  size_t base = (((size_t)b * K_ + k) * NC_ + c) * 513;
  float den = cpre[base];
  float sre = cpre[base + 1 + h * 4 + m];
  float sim = cpre[base + 1 + 256 + h * 4 + m];
  const float theta_v = theta_tab[chk * M_ + m];
  const float w = w_tab[chk * M_ + m];
  const float ts = tanh_scale[k], ss = score_scale[k], slope = slopes_sp[k];
  const float nsv = ns[chk];
  const float gb = gate_b[k];
  const int kq = k >> 1;   // NREP = 2
  float ckv[4], cks[4];
#pragma unroll
  for (int ww = 0; ww < 4; ++ww) { ckv[ww] = ck[ww * ZC_ + chk]; cks[ww] = ck[ww * ZC_ + chs]; }
  const int l0 = c * LC_;
  float zk3 = 0.f, zk2 = 0.f, zk1 = 0.f, zs3 = 0.f, zs2 = 0.f, zs1 = 0.f;
#pragma unroll
  for (int p = 0; p < 3; ++p) {
    int lp = l0 - 3 + p;
    if (lp >= 0) {
      size_t tp = (size_t)b * L_ + lp;
      float zk = zp[tp * ZC_ + chk], zs = zp[tp * ZC_ + chs];
      if (p == 0) { zk3 = zk; zs3 = zs; }
      else if (p == 1) { zk2 = zk; zs2 = zs; }
      else { zk1 = zk; zs1 = zs; }
    }
  }
  const int qidx = ((kq * H_ + h) * M_ + m) * 2;
  for (int ll = 0; ll < LC_; ++ll) {
    int l = l0 + ll;
    size_t t = (size_t)b * L_ + l;
    float zk0 = zp[t * ZC_ + chk];
    float zs0 = zp[t * ZC_ + chs];
    float kv = zk3 * ckv[0] + zk2 * ckv[1] + zk1 * ckv[2] + zk0 * ckv[3];
    float sraw = zs3 * cks[0] + zs2 * cks[1] + zs1 * cks[2] + zs0 * cks[3];
    zk3 = zk2; zk2 = zk1; zk1 = zk0;
    zs3 = zs2; zs2 = zs1; zs1 = zs0;
    float lp = fminf(fmaxf(ss * sraw, -20.f), 20.f);
    float pw = __expf(lp - slope * (float)(L_ - 1 - l));
    float ph = fast_tanh(ts * kv) * theta_v;
    float kvp = kv * pw;
    sre += kvp * __cosf(ph);
    sim += kvp * __sinf(ph);
    den += pw;
    float inv = 1.f / fmaxf(den, 1e-4f);
    float s_re = sre * inv, s_im = sim * inv;
    size_t qb = t * QST_ + qidx;
    float qr = (float)qh[qb], qi = (float)qh[qb + 1];
    float tr = (s_re * qr + s_im * qi) * w;
    float ti = (s_im * qr - s_re * qi) * w;
    tr += __shfl_xor(tr, 1); tr += __shfl_xor(tr, 2);
    ti += __shfl_xor(ti, 1); ti += __shfl_xor(ti, 2);
    if (m == 0) {
      float g = 1.f / (1.f + __expf(-(gatelin[t * K_ + k] + gb))) * nsv;
      size_t ab = ((size_t)k * NTOK_ + t) * 128;
      asp[ab + h] = (_Float16)(tr * g);
      asp[ab + 64 + h] = (_Float16)(ti * g);
    }
  }
}

// ---------------------------------------------------------------------------
extern "C" void kernel_launch(void* const* d_in, const int* in_sizes, int n_in,
                              void* d_out, int out_size, void* d_ws, size_t ws_size,
                              hipStream_t stream) {
  const float* x            = (const float*)d_in[0];
  const float* W_mem        = (const float*)d_in[1];
  const float* conv_k       = (const float*)d_in[2];
  const float* W_q          = (const float*)d_in[3];
  const float* theta_d_raw  = (const float*)d_in[4];
  const float* decay_slopes = (const float*)d_in[5];
  const float* score_scale  = (const float*)d_in[6];
  const float* tanh_scale   = (const float*)d_in[7];
  const float* W_re         = (const float*)d_in[8];
  const float* W_im         = (const float*)d_in[9];
  const float* norm_scale   = (const float*)d_in[10];
  const float* gate_W       = (const float*)d_in[11];
  const float* gate_b       = (const float*)d_in[12];
  const float* skip_down_W  = (const float*)d_in[13];
  const float* skip_up_W    = (const float*)d_in[14];
  const float* highway_scale= (const float*)d_in[15];
  const float* out_W        = (const float*)d_in[16];
  float* out = (float*)d_out;
  float* ws = (float*)d_ws;

  // ---- f32 region ----
  float* theta_tab = ws;                                  // 3072
  float* w_tab     = theta_tab + 3072;                    // 3072
  float* slopes_sp = w_tab + 3072;                        // 16
  float* z_pre     = slopes_sp + 16;                      // 3,194,880
  float* gatelin   = z_pre + (size_t)NTOK_ * ZC_;         // 49,152
  float* csums     = gatelin + (size_t)NTOK_ * K_;        // 787,968
  float* cpre      = csums + (size_t)B_ * K_ * NC_ * 513; // 787,968
  _Float16* q_h    = (_Float16*)(cpre + (size_t)B_ * K_ * NC_ * 513); // 4096x3072
  _Float16* y_h    = q_h + (size_t)NTOK_ * QST_;          // 4096x2304
  float* f32_end   = (float*)(y_h + (size_t)NTOK_ * 2304);

  // ---- fp16 region ----
  _Float16* fp = (_Float16*)f32_end;
  _Float16* x_h    = fp;                fp += (size_t)NTOK_ * D_;
  _Float16* xpb_h  = fp;                fp += (size_t)XPN_ * 768;   // merged proj B (4096 rows)
  _Float16* outw_h = fp;                fp += (size_t)768 * 2304;
  _Float16* asp2_h = fp;                fp += (size_t)K_ * NTOK_ * 128;
  _Float16* bsp_h  = fp;                fp += (size_t)K_ * 384 * 320;
  _Float16* lat_h  = fp;                fp += (size_t)NTOK_ * 192;

  // fused prologue: precomp + all weight conversions (incl gate_W) + out-zero + x->fp16
  prep_kernel<<<18651, 256, 0, stream>>>(x, W_mem, W_q, skip_down_W, out_W, W_re, W_im,
                                         skip_up_W, highway_scale, gate_W,
                                         theta_d_raw, decay_slopes,
                                         out, x_h, xpb_h, outw_h, bsp_h,
                                         theta_tab, w_tab, slopes_sp);

  // merged x-projection (256-tile 8-phase): q + lat + gate + z_pre in ONE dispatch
  xproj256_kernel<<<256, 512, 0, stream>>>(x_h, xpb_h, z_pre, lat_h, q_h, gatelin);

  // chunked scan (f32) with fused causal conv
  pass_a_kernel<<<dim3(NC_, K_, B_), 256, 0, stream>>>(z_pre, conv_k, theta_tab, score_scale,
                                                       tanh_scale, slopes_sp, csums);
  pass_b_kernel<<<dim3(9, B_ * K_), 64, 0, stream>>>(csums, cpre);
  pass_c_kernel<<<dim3(NC_, K_, B_), 256, 0, stream>>>(z_pre, conv_k, q_h, theta_tab, w_tab,
                                                       score_scale, tanh_scale, slopes_sp, cpre,
                                                       gatelin, gate_b, norm_scale, asp2_h);

  // batched spec GEMM (A = [asp2 per-k | lat_h shared], hs folded into bsp)
  // with fused SiLU -> y_h fp16; XCD-chunked 1D grid (3x32x12 blocks)
  mfma_gemm_kernel<0, 1><<<1152, 256, 0, stream>>>(asp2_h, bsp_h, nullptr,
                                                   320, 384,
                                                   (long)NTOK_ * 128, 384L * 320, 0,
                                                   lat_h, y_h, 0, 0, 0);
  // out += y @ out_W  (split-K=4, atomic, XCD-swizzled 1D grid)
  mfma_gemm_kernel<1, 0><<<768, 256, 0, stream>>>(y_h, outw_h, out,
                                                  2304, 768, 0, 0, 0,
                                                  nullptr, nullptr, 6, 32, 4);
}

// Round 4
// 278.305 us; speedup vs baseline: 1.1642x; 1.0689x over previous
//
#include <hip/hip_runtime.h>
#include <math.h>

#define B_    2
#define L_    2048
#define D_    768
#define K_    12
#define KQ_   6
#define M_    4
#define H_    64
#define ZC_   780      // MEM + K
#define NTOK_ 4096     // B*L
#define NC_   64       // scan chunks per batch
#define LC_   32       // chunk length (L/NC)
#define QST_  3072     // q fp16 row stride
#define XPN_  4096     // merged projection N (exactly 16 x 256 tiles -> no grid tail)
#define ZOFF_ 3276     // z_pre column base in xpb

typedef __attribute__((ext_vector_type(8))) _Float16 half8;
typedef __attribute__((ext_vector_type(4))) float f32x4;

__device__ __forceinline__ float softplus_f(float x) {
  return (x > 20.f) ? x : log1pf(expf(x));
}

__device__ __forceinline__ float fast_tanh(float x) {
  float xx = fminf(fmaxf(x, -10.f), 10.f);
  float e = __expf(2.f * xx);
  return (e - 1.f) / (e + 1.f);
}

// async global->LDS 16B per lane (dest = wave-uniform base + lane*16)
__device__ __forceinline__ void async16(const _Float16* g, _Float16* l) {
  __builtin_amdgcn_global_load_lds(
      (const __attribute__((address_space(1))) unsigned int*)g,
      (__attribute__((address_space(3))) unsigned int*)l, 16, 0, 0);
}

// val/gate 16-interleave permutation for spec-B columns
__device__ __forceinline__ int permcol(int n) {
  int isg = (n >= 192) ? 1 : 0;
  int j = n - 192 * isg;
  return (j >> 4) * 32 + (isg << 4) + (j & 15);
}

#define FENCE() asm volatile("" ::: "memory")

// ---------------------------------------------------------------------------
// Transpose+convert body; optional perm + scale. Nst = store-row limit.
// ---------------------------------------------------------------------------
__device__ __forceinline__ void cvt_t_body(float (*tile)[33], int bx, int by, int kz,
                                           const float* src, long sKs, int srs,
                                           _Float16* dh, long dKs, int dst, int doff,
                                           int R, int Nact, int Nst, bool perm, float scale) {
  const float* s = src + (size_t)kz * sKs;
  _Float16* dhh = dh + (size_t)kz * dKs;
  const int kb = bx * 32;
  const int nb = by * 32;
  const int tx = threadIdx.x & 31, ty = threadIdx.x >> 5;
  for (int i = ty; i < 32; i += 8) {
    int kk = kb + i, n = nb + tx;
    tile[i][tx] = (kk < R && n < Nact) ? s[(size_t)kk * srs + n] : 0.f;
  }
  __syncthreads();
  for (int i = ty; i < 32; i += 8) {
    int n = nb + i, kk = kb + tx;
    if (kk < R && n < Nst) {
      float v = tile[tx][i] * scale;
      int dn = perm ? permcol(n) : n;
      dhh[(size_t)dn * dst + doff + kk] = (_Float16)v;
    }
  }
}

// ---------------------------------------------------------------------------
// Fused prologue, ONE dispatch:
//   blocks [0,3):          precomp (theta/w tables, slopes)
//   blocks [3,6363):       all weight conversions (incl. gate_W -> xpb cols)
//   blocks [6363,18651):   x f32->fp16
// xpb layout (rows x 768): [W_q^T 0:3072 | skd^T 3072:3264 | gate^T 3264:3276 |
//                           W_mem^T 3276:4056 | dead 4056:4096]
// ---------------------------------------------------------------------------
__global__ __launch_bounds__(256)
void prep_kernel(const float* __restrict__ x,
                 const float* __restrict__ W_mem, const float* __restrict__ W_q,
                 const float* __restrict__ skip_down_W, const float* __restrict__ out_W,
                 const float* __restrict__ W_re, const float* __restrict__ W_im,
                 const float* __restrict__ skip_up_W, const float* __restrict__ hs,
                 const float* __restrict__ gate_W,
                 const float* __restrict__ theta_d_raw, const float* __restrict__ decay,
                 _Float16* __restrict__ x_h,
                 _Float16* __restrict__ xpb_h, _Float16* __restrict__ outw_h,
                 _Float16* __restrict__ bsp_h,
                 float* __restrict__ theta_tab, float* __restrict__ w_tab,
                 float* __restrict__ slopes_sp) {
  __shared__ float tile[32][33];
  int b = blockIdx.x;
  if (b < 3) {
    int idx = b * 256 + threadIdx.x;
    if (idx < K_) slopes_sp[idx] = softplus_f(decay[idx]);
    if (idx >= K_ * H_) return;
    float td[M_], ta[M_];
#pragma unroll
    for (int m = 0; m < M_; ++m) td[m] = softplus_f(theta_d_raw[idx * M_ + m]) + 1e-4f;
    ta[0] = td[0];
#pragma unroll
    for (int m = 1; m < M_; ++m) ta[m] = ta[m - 1] + td[m];
    float total = ta[M_ - 1];
    float rs = 2.999f / total;
#pragma unroll
    for (int m = 0; m < M_; ++m) theta_tab[idx * M_ + m] = 0.001f + ta[m] * rs;
    float d0 = (ta[1] - ta[0]) * rs;
    float d1 = (ta[2] - ta[1]) * rs;
    float d2 = (ta[3] - ta[2]) * rs;
    w_tab[idx * M_ + 0] = 0.5f * d0;
    w_tab[idx * M_ + 1] = 0.5f * (d0 + d1);
    w_tab[idx * M_ + 2] = 0.5f * (d1 + d2);
    w_tab[idx * M_ + 3] = 0.5f * d2;
    return;
  }
  b -= 3;
  if (b < 6360) {
    if (b < 672) {           // W_mem -> xpb rows [3276,4056), 24x28
      cvt_t_body(tile, b % 24, b / 24, 0, W_mem, 0, ZC_, xpb_h + (size_t)ZOFF_ * 768,
                 0, 768, 0, 768, ZC_, ZC_, false, 1.f);
      return;
    }
    b -= 672;
    if (b < 2304) {          // W_q -> xpb rows [0,3072), 24x96
      cvt_t_body(tile, b % 24, b / 24, 0, W_q, 0, 3072, xpb_h, 0, 768, 0, 768,
                 3072, 3072, false, 1.f);
      return;
    }
    b -= 2304;
    if (b < 192) {           // skip_down -> xpb rows [3072,3264), 24x8
      cvt_t_body(tile, b % 24, b / 24, 0, skip_down_W, 0, 192, xpb_h + (size_t)3072 * 768,
                 0, 768, 0, 768, 192, 192, false, 1.f);
      return;
    }
    b -= 192;
    if (b < 1728) {          // out_W -> outw, 72x24
      cvt_t_body(tile, b % 72, b / 72, 0, out_W, 0, 768, outw_h, 0, 2304, 0, 2304,
                 768, 768, false, 1.f);
      return;
    }
    b -= 1728;
    if (b < 288) {           // W_re -> bsp[k][perm(n)][0:64], 2x12x12
      cvt_t_body(tile, b % 2, (b / 2) % 12, b / 24, W_re, 64L * 384, 384, bsp_h,
                 384L * 320, 320, 0, 64, 384, 384, true, 1.f);
      return;
    }
    b -= 288;
    if (b < 288) {           // W_im -> bsp[k][perm(n)][64:128]
      cvt_t_body(tile, b % 2, (b / 2) % 12, b / 24, W_im, 64L * 384, 384, bsp_h,
                 384L * 320, 320, 64, 64, 384, 384, true, 1.f);
      return;
    }
    b -= 288;
    if (b < 864) {           // skip_up slice -> bsp[k][perm(n)][128:320] scaled by hs[k]
      int kz = b / 72;
      cvt_t_body(tile, b % 6, (b / 6) % 12, kz, skip_up_W, 384, 4608, bsp_h,
                 384L * 320, 320, 128, 192, 384, 384, true, hs[kz]);
      return;
    }
    b -= 864;
    // gate_W (768x12) -> xpb rows [3264,3276), 24 blocks; store-limited to 12 rows
    cvt_t_body(tile, b, 0, 0, gate_W, 0, K_, xpb_h + (size_t)3264 * 768,
               0, 768, 0, 768, K_, K_, false, 1.f);
    return;
  }
  b -= 6360;
  size_t i = (size_t)b * 256 + threadIdx.x;
  if (i < (size_t)NTOK_ * D_) {
    x_h[i] = (_Float16)x[i];         // x -> fp16
  }
}

// ---------------------------------------------------------------------------
// 256x256-tile 8-phase deep-pipelined MFMA GEMM for the merged x-projection.
// M=4096, N=4096, K=768, BK=64, 12 K-tiles, 512 threads (8 waves 2Mx4N),
// 128 KiB dbuf LDS, two [128][32] subtiles per K-half (0-conflict swizzle).
// Grid = 256 blocks = exactly 1 block/CU.
// ---------------------------------------------------------------------------
__global__ __launch_bounds__(512, 2)
void xproj256_kernel(const _Float16* __restrict__ Ah, const _Float16* __restrict__ Bh,
                     float* __restrict__ C, _Float16* __restrict__ YH,
                     _Float16* __restrict__ QH, float* __restrict__ GL) {
  // [dbuf][Mhalf/Nhalf][Khalf][row][col32]
  __shared__ __align__(16) _Float16 sA[2][2][2][128][32];
  __shared__ __align__(16) _Float16 sB[2][2][2][128][32];

  const int bid = blockIdx.x;
  const int xcd = bid & 7, s = bid >> 3;        // s in [0,32)
  const int by = xcd * 2 + (s & 1);             // 0..15
  const int bx = s >> 1;                        // 0..15
  const int bm0 = by * 256, bn0 = bx * 256;

  const int tid = threadIdx.x;
  const int lane = tid & 63;
  const int wave = tid >> 6;
  const int m16 = lane & 15, quad = lane >> 4;
  const int wr = wave >> 2;          // 0..1 A-half
  const int wc = wave & 3;           // 0..3 B col group (64 cols)
  const int bhalf = wc >> 1;         // B LDS half
  const int brow0 = (wc & 1) * 64;   // row base within B half

  f32x4 acc[8][4];
#pragma unroll
  for (int i = 0; i < 8; ++i)
#pragma unroll
    for (int j = 0; j < 4; ++j) acc[i][j] = (f32x4){0.f, 0.f, 0.f, 0.f};

  const int sr = tid >> 2;           // 0..127
  const int lb = tid & 3;            // 16B block within 32-half subtile row
  const int ssw = (sr >> 1) & 3;     // row swizzle term

  auto stageA = [&](int t, int h) {
    const int bb = t & 1;
    const _Float16* g = Ah + (size_t)(bm0 + h * 128 + sr) * 768 + t * 64
                        + ((lb ^ ssw) << 3);
    async16(g,      &sA[bb][h][0][0][0] + (size_t)tid * 8);
    async16(g + 32, &sA[bb][h][1][0][0] + (size_t)tid * 8);
  };
  auto stageB = [&](int t, int h) {
    const int bb = t & 1;
    const _Float16* g = Bh + (size_t)(bn0 + h * 128 + sr) * 768 + t * 64
                        + ((lb ^ ssw) << 3);
    async16(g,      &sB[bb][h][0][0][0] + (size_t)tid * 8);
    async16(g + 32, &sB[bb][h][1][0][0] + (size_t)tid * 8);
  };

  auto ldA = [&](int bb, int r, int kk) -> half8 {
    return *(const half8*)&sA[bb][wr][kk][r][(quad ^ ((r >> 1) & 3)) << 3];
  };
  auto ldB = [&](int bb, int r, int kk) -> half8 {
    return *(const half8*)&sB[bb][bhalf][kk][r][(quad ^ ((r >> 1) & 3)) << 3];
  };

  half8 aLo[8], aHi[8], bLo[4], bHi[4];

  stageB(0, 0); stageB(0, 1); stageA(0, 0); stageA(0, 1);
  stageB(1, 0); stageB(1, 1); stageA(1, 0); stageA(1, 1);
  __builtin_amdgcn_s_waitcnt(0x0F78);   // vmcnt(8): K-tile 0 landed
  FENCE(); __builtin_amdgcn_s_barrier(); FENCE();
#pragma unroll
  for (int m = 0; m < 4; ++m)
#pragma unroll
    for (int kk = 0; kk < 2; ++kk) aLo[m * 2 + kk] = ldA(0, m * 16 + m16, kk);
#pragma unroll
  for (int n = 0; n < 2; ++n)
#pragma unroll
    for (int kk = 0; kk < 2; ++kk) bLo[n * 2 + kk] = ldB(0, brow0 + n * 16 + m16, kk);

  for (int t = 0; t < 12; ++t) {
    const int bb = t & 1;
    const int nb = bb ^ 1;
    // ---------- phase 0: read bHi(t); MFMA lo-lo ----------
#pragma unroll
    for (int n = 0; n < 2; ++n)
#pragma unroll
      for (int kk = 0; kk < 2; ++kk)
        bHi[n * 2 + kk] = ldB(bb, brow0 + (n + 2) * 16 + m16, kk);
    FENCE(); __builtin_amdgcn_s_barrier(); FENCE();
    __builtin_amdgcn_s_setprio(1);
#pragma unroll
    for (int m = 0; m < 4; ++m)
#pragma unroll
      for (int n = 0; n < 2; ++n)
#pragma unroll
        for (int kk = 0; kk < 2; ++kk)
          acc[m][n] = __builtin_amdgcn_mfma_f32_16x16x32_f16(aLo[m * 2 + kk], bLo[n * 2 + kk],
                                                             acc[m][n], 0, 0, 0);
    __builtin_amdgcn_s_setprio(0);
    FENCE(); __builtin_amdgcn_s_barrier(); FENCE();
    // ---------- phase 1: read aHi(t); MFMA lo-hi; drain vmcnt ----------
#pragma unroll
    for (int m = 0; m < 4; ++m)
#pragma unroll
      for (int kk = 0; kk < 2; ++kk)
        aHi[m * 2 + kk] = ldA(bb, 64 + m * 16 + m16, kk);
    FENCE(); __builtin_amdgcn_s_barrier(); FENCE();
    __builtin_amdgcn_s_setprio(1);
#pragma unroll
    for (int m = 0; m < 4; ++m)
#pragma unroll
      for (int n = 2; n < 4; ++n)
#pragma unroll
        for (int kk = 0; kk < 2; ++kk)
          acc[m][n] = __builtin_amdgcn_mfma_f32_16x16x32_f16(aLo[m * 2 + kk], bHi[(n - 2) * 2 + kk],
                                                             acc[m][n], 0, 0, 0);
    __builtin_amdgcn_s_setprio(0);
    __builtin_amdgcn_s_waitcnt(0x0F70);   // vmcnt(0): K-tile t+1 landed
    FENCE(); __builtin_amdgcn_s_barrier(); FENCE();
    // ---------- phase 2: read aLo(t+1); stage B(t+2); MFMA hi-lo ----------
    if (t < 11) {
#pragma unroll
      for (int m = 0; m < 4; ++m)
#pragma unroll
        for (int kk = 0; kk < 2; ++kk)
          aLo[m * 2 + kk] = ldA(nb, m * 16 + m16, kk);
    }
    if (t < 10) { stageB(t + 2, 0); stageB(t + 2, 1); }
    FENCE(); __builtin_amdgcn_s_barrier(); FENCE();
    __builtin_amdgcn_s_setprio(1);
#pragma unroll
    for (int m = 0; m < 4; ++m)
#pragma unroll
      for (int n = 0; n < 2; ++n)
#pragma unroll
        for (int kk = 0; kk < 2; ++kk)
          acc[m + 4][n] = __builtin_amdgcn_mfma_f32_16x16x32_f16(aHi[m * 2 + kk], bLo[n * 2 + kk],
                                                                 acc[m + 4][n], 0, 0, 0);
    __builtin_amdgcn_s_setprio(0);
    FENCE(); __builtin_amdgcn_s_barrier(); FENCE();
    // ---------- phase 3: read bLo(t+1); stage A(t+2); MFMA hi-hi ----------
    if (t < 11) {
#pragma unroll
      for (int n = 0; n < 2; ++n)
#pragma unroll
        for (int kk = 0; kk < 2; ++kk)
          bLo[n * 2 + kk] = ldB(nb, brow0 + n * 16 + m16, kk);
    }
    if (t < 10) { stageA(t + 2, 0); stageA(t + 2, 1); }
    FENCE(); __builtin_amdgcn_s_barrier(); FENCE();
    __builtin_amdgcn_s_setprio(1);
#pragma unroll
    for (int m = 0; m < 4; ++m)
#pragma unroll
      for (int n = 2; n < 4; ++n)
#pragma unroll
        for (int kk = 0; kk < 2; ++kk)
          acc[m + 4][n] = __builtin_amdgcn_mfma_f32_16x16x32_f16(aHi[m * 2 + kk], bHi[(n - 2) * 2 + kk],
                                                                 acc[m + 4][n], 0, 0, 0);
    __builtin_amdgcn_s_setprio(0);
    FENCE(); __builtin_amdgcn_s_barrier(); FENCE();
  }

  // ---- epilogue (C/D layout: col=lane&15, row=quad*4+reg) ----
#pragma unroll
  for (int m = 0; m < 8; ++m) {
    const int row0 = bm0 + wr * 128 + m * 16 + quad * 4;
#pragma unroll
    for (int n = 0; n < 4; ++n) {
      const int col = bn0 + wc * 64 + n * 16 + m16;
      if (col < 3072) {
#pragma unroll
        for (int r = 0; r < 4; ++r)
          QH[(size_t)(row0 + r) * QST_ + col] = (_Float16)acc[m][n][r];
      } else if (col < 3264) {
        const int jj = col - 3072;
#pragma unroll
        for (int r = 0; r < 4; ++r)
          YH[(size_t)(row0 + r) * 192 + jj] = (_Float16)acc[m][n][r];
      } else if (col < 3276) {
        const int kk = col - 3264;
#pragma unroll
        for (int r = 0; r < 4; ++r)
          GL[(size_t)(row0 + r) * K_ + kk] = acc[m][n][r];
      } else if (col < 3276 + ZC_) {
        const int wz = col - ZOFF_;
#pragma unroll
        for (int r = 0; r < 4; ++r)
          C[(size_t)(row0 + r) * ZC_ + wz] = acc[m][n][r];
      }
    }
  }
}

// ---------------------------------------------------------------------------
// 256x256-tile 8-phase out-projection GEMM: out = y @ out_W.
// M=4096, N=768 (=3x256 exact), K=2304, split-K=4 (576 each = 9 BK-tiles).
// Grid 192 blocks x 512 thr, one round, NO atomics: split 0 stores to out,
// splits 1-3 store f32 partials (overlaid on dead scan workspace);
// redout_kernel folds partials into out.
// XCD chunking: xcd owns contiguous g-range -> B panel (bx,kz) L2-resident.
// ---------------------------------------------------------------------------
__global__ __launch_bounds__(512, 2)
void outproj256_kernel(const _Float16* __restrict__ Ah, const _Float16* __restrict__ Bh,
                       float* __restrict__ out, float* __restrict__ part) {
  __shared__ __align__(16) _Float16 sA[2][2][2][128][32];
  __shared__ __align__(16) _Float16 sB[2][2][2][128][32];

  const int bid = blockIdx.x;
  const int xcd = bid & 7, s = bid >> 3;        // s in [0,24)
  const int g = xcd * 24 + s;                   // contiguous per XCD
  const int by = g & 15;
  const int c = g >> 4;                         // 0..11
  const int kz = c >> 2;                        // wrong if c%? -- use /3 mapping below
  // c = kz*3 + bx with kz in [0,4), bx in [0,3)
  const int kz_ = c / 3, bx = c - kz_ * 3;
  const int bm0 = by * 256, bn0 = bx * 256;
  const int kt0 = kz_ * 9;                      // first BK-tile (of 64) for this split

  const int tid = threadIdx.x;
  const int lane = tid & 63;
  const int wave = tid >> 6;
  const int m16 = lane & 15, quad = lane >> 4;
  const int wr = wave >> 2;
  const int wc = wave & 3;
  const int bhalf = wc >> 1;
  const int brow0 = (wc & 1) * 64;

  f32x4 acc[8][4];
#pragma unroll
  for (int i = 0; i < 8; ++i)
#pragma unroll
    for (int j = 0; j < 4; ++j) acc[i][j] = (f32x4){0.f, 0.f, 0.f, 0.f};

  const int sr = tid >> 2;
  const int lbk = tid & 3;
  const int ssw = (sr >> 1) & 3;

  auto stageA = [&](int lt, int h) {
    const int bb = lt & 1;
    const _Float16* gp = Ah + (size_t)(bm0 + h * 128 + sr) * 2304 + (kt0 + lt) * 64
                         + ((lbk ^ ssw) << 3);
    async16(gp,      &sA[bb][h][0][0][0] + (size_t)tid * 8);
    async16(gp + 32, &sA[bb][h][1][0][0] + (size_t)tid * 8);
  };
  auto stageB = [&](int lt, int h) {
    const int bb = lt & 1;
    const _Float16* gp = Bh + (size_t)(bn0 + h * 128 + sr) * 2304 + (kt0 + lt) * 64
                         + ((lbk ^ ssw) << 3);
    async16(gp,      &sB[bb][h][0][0][0] + (size_t)tid * 8);
    async16(gp + 32, &sB[bb][h][1][0][0] + (size_t)tid * 8);
  };

  auto ldA = [&](int bb, int r, int kk) -> half8 {
    return *(const half8*)&sA[bb][wr][kk][r][(quad ^ ((r >> 1) & 3)) << 3];
  };
  auto ldB = [&](int bb, int r, int kk) -> half8 {
    return *(const half8*)&sB[bb][bhalf][kk][r][(quad ^ ((r >> 1) & 3)) << 3];
  };

  half8 aLo[8], aHi[8], bLo[4], bHi[4];

  stageB(0, 0); stageB(0, 1); stageA(0, 0); stageA(0, 1);
  stageB(1, 0); stageB(1, 1); stageA(1, 0); stageA(1, 1);
  __builtin_amdgcn_s_waitcnt(0x0F78);   // vmcnt(8)
  FENCE(); __builtin_amdgcn_s_barrier(); FENCE();
#pragma unroll
  for (int m = 0; m < 4; ++m)
#pragma unroll
    for (int kk = 0; kk < 2; ++kk) aLo[m * 2 + kk] = ldA(0, m * 16 + m16, kk);
#pragma unroll
  for (int n = 0; n < 2; ++n)
#pragma unroll
    for (int kk = 0; kk < 2; ++kk) bLo[n * 2 + kk] = ldB(0, brow0 + n * 16 + m16, kk);

  for (int t = 0; t < 9; ++t) {
    const int bb = t & 1;
    const int nb = bb ^ 1;
    // phase 0
#pragma unroll
    for (int n = 0; n < 2; ++n)
#pragma unroll
      for (int kk = 0; kk < 2; ++kk)
        bHi[n * 2 + kk] = ldB(bb, brow0 + (n + 2) * 16 + m16, kk);
    FENCE(); __builtin_amdgcn_s_barrier(); FENCE();
    __builtin_amdgcn_s_setprio(1);
#pragma unroll
    for (int m = 0; m < 4; ++m)
#pragma unroll
      for (int n = 0; n < 2; ++n)
#pragma unroll
        for (int kk = 0; kk < 2; ++kk)
          acc[m][n] = __builtin_amdgcn_mfma_f32_16x16x32_f16(aLo[m * 2 + kk], bLo[n * 2 + kk],
                                                             acc[m][n], 0, 0, 0);
    __builtin_amdgcn_s_setprio(0);
    FENCE(); __builtin_amdgcn_s_barrier(); FENCE();
    // phase 1
#pragma unroll
    for (int m = 0; m < 4; ++m)
#pragma unroll
      for (int kk = 0; kk < 2; ++kk)
        aHi[m * 2 + kk] = ldA(bb, 64 + m * 16 + m16, kk);
    FENCE(); __builtin_amdgcn_s_barrier(); FENCE();
    __builtin_amdgcn_s_setprio(1);
#pragma unroll
    for (int m = 0; m < 4; ++m)
#pragma unroll
      for (int n = 2; n < 4; ++n)
#pragma unroll
        for (int kk = 0; kk < 2; ++kk)
          acc[m][n] = __builtin_amdgcn_mfma_f32_16x16x32_f16(aLo[m * 2 + kk], bHi[(n - 2) * 2 + kk],
                                                             acc[m][n], 0, 0, 0);
    __builtin_amdgcn_s_setprio(0);
    __builtin_amdgcn_s_waitcnt(0x0F70);   // vmcnt(0)
    FENCE(); __builtin_amdgcn_s_barrier(); FENCE();
    // phase 2
    if (t < 8) {
#pragma unroll
      for (int m = 0; m < 4; ++m)
#pragma unroll
        for (int kk = 0; kk < 2; ++kk)
          aLo[m * 2 + kk] = ldA(nb, m * 16 + m16, kk);
    }
    if (t < 7) { stageB(t + 2, 0); stageB(t + 2, 1); }
    FENCE(); __builtin_amdgcn_s_barrier(); FENCE();
    __builtin_amdgcn_s_setprio(1);
#pragma unroll
    for (int m = 0; m < 4; ++m)
#pragma unroll
      for (int n = 0; n < 2; ++n)
#pragma unroll
        for (int kk = 0; kk < 2; ++kk)
          acc[m + 4][n] = __builtin_amdgcn_mfma_f32_16x16x32_f16(aHi[m * 2 + kk], bLo[n * 2 + kk],
                                                                 acc[m + 4][n], 0, 0, 0);
    __builtin_amdgcn_s_setprio(0);
    FENCE(); __builtin_amdgcn_s_barrier(); FENCE();
    // phase 3
    if (t < 8) {
#pragma unroll
      for (int n = 0; n < 2; ++n)
#pragma unroll
        for (int kk = 0; kk < 2; ++kk)
          bLo[n * 2 + kk] = ldB(nb, brow0 + n * 16 + m16, kk);
    }
    if (t < 7) { stageA(t + 2, 0); stageA(t + 2, 1); }
    FENCE(); __builtin_amdgcn_s_barrier(); FENCE();
    __builtin_amdgcn_s_setprio(1);
#pragma unroll
    for (int m = 0; m < 4; ++m)
#pragma unroll
      for (int n = 2; n < 4; ++n)
#pragma unroll
        for (int kk = 0; kk < 2; ++kk)
          acc[m + 4][n] = __builtin_amdgcn_mfma_f32_16x16x32_f16(aHi[m * 2 + kk], bHi[(n - 2) * 2 + kk],
                                                                 acc[m + 4][n], 0, 0, 0);
    __builtin_amdgcn_s_setprio(0);
    FENCE(); __builtin_amdgcn_s_barrier(); FENCE();
  }

  // ---- epilogue: plain f32 stores (no atomics) ----
  float* dst = (kz_ == 0) ? out : part + (size_t)(kz_ - 1) * NTOK_ * 768;
#pragma unroll
  for (int m = 0; m < 8; ++m) {
    const int row0 = bm0 + wr * 128 + m * 16 + quad * 4;
#pragma unroll
    for (int n = 0; n < 4; ++n) {
      const int col = bn0 + wc * 64 + n * 16 + m16;
#pragma unroll
      for (int r = 0; r < 4; ++r)
        dst[(size_t)(row0 + r) * 768 + col] = acc[m][n][r];
    }
  }
  (void)kz;
}

// ---------------------------------------------------------------------------
// Fold the 3 split-K partials into out (float4 vectorized, one pass).
// 4096*768 f32 = 786432 float4 -> 3072 blocks x 256 thr.
// ---------------------------------------------------------------------------
__global__ __launch_bounds__(256)
void redout_kernel(float* __restrict__ o, const float* __restrict__ p) {
  const size_t i = (size_t)blockIdx.x * 256 + threadIdx.x;
  const f32x4* pv = (const f32x4*)p;
  f32x4 v = ((const f32x4*)o)[i];
  v += pv[i];
  v += pv[i + 786432];
  v += pv[i + 2 * 786432];
  ((f32x4*)o)[i] = v;
}

// ---------------------------------------------------------------------------
// MFMA fp16 GEMM (128x128, 2-phase): spec GEMM.
// A from split source (asp per-k 128-stride k<128, lat shared 192-stride);
// fused val/gate SiLU -> YH; XCD-chunked 1D grid (3bx x 32by x 12kz).
// ---------------------------------------------------------------------------
__global__ __launch_bounds__(256)
void spec_gemm_kernel(const _Float16* __restrict__ Ah, const _Float16* __restrict__ Bh,
                      const _Float16* __restrict__ A2, _Float16* __restrict__ YH) {
  __shared__ __align__(16) _Float16 sA[2][128 * 32];
  __shared__ __align__(16) _Float16 sB[2][128 * 32];
  const int Kd = 320;
  int bid = blockIdx.x;
  int xcd = bid & 7, s = bid >> 3;        // s in [0,144)
  int kz = s / 12;
  int w = s % 12;
  int bx = w % 3;
  int by = (xcd << 2) + w / 3;
  const _Float16* A0 = Ah + (size_t)kz * ((size_t)NTOK_ * 128);
  const _Float16* B0 = Bh + (size_t)kz * (384L * 320);
  const int bm0 = by * 128;
  const int bn0 = bx * 128;
  const int tid = threadIdx.x;
  const int wave = tid >> 6, lane = tid & 63;
  const int m16 = lane & 15, quad = lane >> 4;
  const int wr = (wave & 1) * 64, wc = (wave >> 1) * 64;

  f32x4 acc[4][4];
#pragma unroll
  for (int i = 0; i < 4; ++i)
#pragma unroll
    for (int j = 0; j < 4; ++j) acc[i][j] = (f32x4){0.f, 0.f, 0.f, 0.f};

  const int lin = tid * 8;
  const int lrow = lin >> 5;
  const int lblk = (lin >> 3) & 3;
  const int csw = ((lblk ^ ((lrow >> 1) & 3)) << 3);

  auto stage = [&](int k0, int kb) {
    if (k0 < 128) {
      const _Float16* gA = A0 + (size_t)(bm0 + lrow) * 128 + (k0 + csw);
      async16(gA, &sA[kb][lin]);
      async16(gA + (size_t)64 * 128, &sA[kb][lin + 2048]);
    } else {
      const _Float16* gA = A2 + (size_t)(bm0 + lrow) * 192 + (k0 - 128 + csw);
      async16(gA, &sA[kb][lin]);
      async16(gA + (size_t)64 * 192, &sA[kb][lin + 2048]);
    }
    const _Float16* gB = B0 + (size_t)(bn0 + lrow) * Kd + (k0 + csw);
    async16(gB, &sB[kb][lin]);
    async16(gB + (size_t)64 * Kd, &sB[kb][lin + 2048]);
  };

  const int niter = Kd / 32;
  stage(0, 0);
  stage(32, 1);

  for (int it = 0; it < niter; ++it) {
    if (it == niter - 1)
      __builtin_amdgcn_s_waitcnt(0x0F70);   // vmcnt(0)
    else
      __builtin_amdgcn_s_waitcnt(0x0F74);   // vmcnt(4)
    __builtin_amdgcn_s_barrier();
    asm volatile("" ::: "memory");
    const int kb = it & 1;
    half8 a0[4], b0[4];
#pragma unroll
    for (int i = 0; i < 4; ++i) {
      const int rA = wr + i * 16 + m16;
      a0[i] = *(const half8*)&sA[kb][rA * 32 + ((quad ^ ((rA >> 1) & 3)) << 3)];
    }
#pragma unroll
    for (int j = 0; j < 4; ++j) {
      const int rB = wc + j * 16 + m16;
      b0[j] = *(const half8*)&sB[kb][rB * 32 + ((quad ^ ((rB >> 1) & 3)) << 3)];
    }
#pragma unroll
    for (int i = 0; i < 4; ++i)
#pragma unroll
      for (int j = 0; j < 4; ++j)
        acc[i][j] = __builtin_amdgcn_mfma_f32_16x16x32_f16(a0[i], b0[j], acc[i][j], 0, 0, 0);
    asm volatile("" ::: "memory");
    __builtin_amdgcn_s_barrier();
    asm volatile("" ::: "memory");
    if (it + 2 < niter) stage((it + 2) * 32, kb);
  }

#pragma unroll
  for (int i = 0; i < 4; ++i) {
    const int row0 = bm0 + wr + i * 16 + quad * 4;
#pragma unroll
    for (int j = 0; j < 4; j += 2) {
      const int colv = bn0 + wc + j * 16 + m16;
      const int jout = (colv >> 5) * 16 + m16;
#pragma unroll
      for (int r = 0; r < 4; ++r) {
        float val = acc[i][j][r];
        float gg = acc[i][j + 1][r];
        float sg = gg / (1.f + __expf(-gg));
        YH[(size_t)(row0 + r) * 2304 + kz * 192 + jout] = (_Float16)(val * sg);
      }
    }
  }
}

// ---------------------------------------------------------------------------
// Scan pass A with fused causal conv (sliding 4-tap window over z_pre)
// ---------------------------------------------------------------------------
__global__ void pass_a_kernel(const float* __restrict__ zp,
                              const float* __restrict__ ck,
                              const float* __restrict__ theta_tab,
                              const float* __restrict__ score_scale,
                              const float* __restrict__ tanh_scale,
                              const float* __restrict__ slopes_sp,
                              float* __restrict__ csums) {
  const int c = blockIdx.x, k = blockIdx.y, b = blockIdx.z;
  const int tid = threadIdx.x;
  const int m = tid & 3, h = tid >> 2;
  const int chk = k * H_ + h;
  const int chs = 768 + k;
  const float theta_v = theta_tab[chk * M_ + m];
  const float ts = tanh_scale[k], ss = score_scale[k], slope = slopes_sp[k];
  float ckv[4], cks[4];
#pragma unroll
  for (int w = 0; w < 4; ++w) { ckv[w] = ck[w * ZC_ + chk]; cks[w] = ck[w * ZC_ + chs]; }
  const int l0 = c * LC_;
  float zk3 = 0.f, zk2 = 0.f, zk1 = 0.f, zs3 = 0.f, zs2 = 0.f, zs1 = 0.f;
#pragma unroll
  for (int p = 0; p < 3; ++p) {
    int lp = l0 - 3 + p;
    if (lp >= 0) {
      size_t tp = (size_t)b * L_ + lp;
      float zk = zp[tp * ZC_ + chk], zs = zp[tp * ZC_ + chs];
      if (p == 0) { zk3 = zk; zs3 = zs; }
      else if (p == 1) { zk2 = zk; zs2 = zs; }
      else { zk1 = zk; zs1 = zs; }
    }
  }
  float sre = 0.f, sim = 0.f, dacc = 0.f;
  for (int ll = 0; ll < LC_; ++ll) {
    int l = l0 + ll;
    size_t t = (size_t)b * L_ + l;
    float zk0 = zp[t * ZC_ + chk];
    float zs0 = zp[t * ZC_ + chs];
    float kv = zk3 * ckv[0] + zk2 * ckv[1] + zk1 * ckv[2] + zk0 * ckv[3];
    float sraw = zs3 * cks[0] + zs2 * cks[1] + zs1 * cks[2] + zs0 * cks[3];
    zk3 = zk2; zk2 = zk1; zk1 = zk0;
    zs3 = zs2; zs2 = zs1; zs1 = zs0;
    float lp = fminf(fmaxf(ss * sraw, -20.f), 20.f);
    float pw = __expf(lp - slope * (float)(L_ - 1 - l));
    float ph = fast_tanh(ts * kv) * theta_v;
    float kvp = kv * pw;
    sre += kvp * __cosf(ph);
    sim += kvp * __sinf(ph);
    dacc += pw;
  }
  size_t base = (((size_t)b * K_ + k) * NC_ + c) * 513;
  if (tid == 0) csums[base] = dacc;
  csums[base + 1 + h * 4 + m] = sre;
  csums[base + 1 + 256 + h * 4 + m] = sim;
}

// ---------------------------------------------------------------------------
__global__ void pass_b_kernel(const float* __restrict__ csums,
                              float* __restrict__ cpre) {
  int bk = blockIdx.y;
  int comp = blockIdx.x * 64 + threadIdx.x;
  if (comp >= 513) return;
  float run = 0.f;
  size_t base = (size_t)bk * NC_ * 513 + comp;
  for (int c = 0; c < NC_; ++c) {
    cpre[base + (size_t)c * 513] = run;
    run += csums[base + (size_t)c * 513];
  }
}

// ---------------------------------------------------------------------------
// Scan pass C: fused conv replay, contract with fp16 q, apply ns*gate,
// write fp16 into asp2[k][t][0:128] (128-stride)
// ---------------------------------------------------------------------------
__global__ void pass_c_kernel(const float* __restrict__ zp,
                              const float* __restrict__ ck,
                              const _Float16* __restrict__ qh,
                              const float* __restrict__ theta_tab,
                              const float* __restrict__ w_tab,
                              const float* __restrict__ score_scale,
                              const float* __restrict__ tanh_scale,
                              const float* __restrict__ slopes_sp,
                              const float* __restrict__ cpre,
                              const float* __restrict__ gatelin,
                              const float* __restrict__ gate_b,
                              const float* __restrict__ ns,
                              _Float16* __restrict__ asp) {
  const int c = blockIdx.x, k = blockIdx.y, b = blockIdx.z;
  const int tid = threadIdx.x;
  const int m = tid & 3, h = tid >> 2;
  const int chk = k * H_ + h;
  const int chs = 768 + k;
  size_t base = (((size_t)b * K_ + k) * NC_ + c) * 513;
  float den = cpre[base];
  float sre = cpre[base + 1 + h * 4 + m];
  float sim = cpre[base + 1 + 256 + h * 4 + m];
  const float theta_v = theta_tab[chk * M_ + m];
  const float w = w_tab[chk * M_ + m];
  const float ts = tanh_scale[k], ss = score_scale[k], slope = slopes_sp[k];
  const float nsv = ns[chk];
  const float gb = gate_b[k];
  const int kq = k >> 1;   // NREP = 2
  float ckv[4], cks[4];
#pragma unroll
  for (int ww = 0; ww < 4; ++ww) { ckv[ww] = ck[ww * ZC_ + chk]; cks[ww] = ck[ww * ZC_ + chs]; }
  const int l0 = c * LC_;
  float zk3 = 0.f, zk2 = 0.f, zk1 = 0.f, zs3 = 0.f, zs2 = 0.f, zs1 = 0.f;
#pragma unroll
  for (int p = 0; p < 3; ++p) {
    int lp = l0 - 3 + p;
    if (lp >= 0) {
      size_t tp = (size_t)b * L_ + lp;
      float zk = zp[tp * ZC_ + chk], zs = zp[tp * ZC_ + chs];
      if (p == 0) { zk3 = zk; zs3 = zs; }
      else if (p == 1) { zk2 = zk; zs2 = zs; }
      else { zk1 = zk; zs1 = zs; }
    }
  }
  const int qidx = ((kq * H_ + h) * M_ + m) * 2;
  for (int ll = 0; ll < LC_; ++ll) {
    int l = l0 + ll;
    size_t t = (size_t)b * L_ + l;
    float zk0 = zp[t * ZC_ + chk];
    float zs0 = zp[t * ZC_ + chs];
    float kv = zk3 * ckv[0] + zk2 * ckv[1] + zk1 * ckv[2] + zk0 * ckv[3];
    float sraw = zs3 * cks[0] + zs2 * cks[1] + zs1 * cks[2] + zs0 * cks[3];
    zk3 = zk2; zk2 = zk1; zk1 = zk0;
    zs3 = zs2; zs2 = zs1; zs1 = zs0;
    float lp = fminf(fmaxf(ss * sraw, -20.f), 20.f);
    float pw = __expf(lp - slope * (float)(L_ - 1 - l));
    float ph = fast_tanh(ts * kv) * theta_v;
    float kvp = kv * pw;
    sre += kvp * __cosf(ph);
    sim += kvp * __sinf(ph);
    den += pw;
    float inv = 1.f / fmaxf(den, 1e-4f);
    float s_re = sre * inv, s_im = sim * inv;
    size_t qb = t * QST_ + qidx;
    float qr = (float)qh[qb], qi = (float)qh[qb + 1];
    float tr = (s_re * qr + s_im * qi) * w;
    float ti = (s_im * qr - s_re * qi) * w;
    tr += __shfl_xor(tr, 1); tr += __shfl_xor(tr, 2);
    ti += __shfl_xor(ti, 1); ti += __shfl_xor(ti, 2);
    if (m == 0) {
      float g = 1.f / (1.f + __expf(-(gatelin[t * K_ + k] + gb))) * nsv;
      size_t ab = ((size_t)k * NTOK_ + t) * 128;
      asp[ab + h] = (_Float16)(tr * g);
      asp[ab + 64 + h] = (_Float16)(ti * g);
    }
  }
}

// ---------------------------------------------------------------------------
extern "C" void kernel_launch(void* const* d_in, const int* in_sizes, int n_in,
                              void* d_out, int out_size, void* d_ws, size_t ws_size,
                              hipStream_t stream) {
  const float* x            = (const float*)d_in[0];
  const float* W_mem        = (const float*)d_in[1];
  const float* conv_k       = (const float*)d_in[2];
  const float* W_q          = (const float*)d_in[3];
  const float* theta_d_raw  = (const float*)d_in[4];
  const float* decay_slopes = (const float*)d_in[5];
  const float* score_scale  = (const float*)d_in[6];
  const float* tanh_scale   = (const float*)d_in[7];
  const float* W_re         = (const float*)d_in[8];
  const float* W_im         = (const float*)d_in[9];
  const float* norm_scale   = (const float*)d_in[10];
  const float* gate_W       = (const float*)d_in[11];
  const float* gate_b       = (const float*)d_in[12];
  const float* skip_down_W  = (const float*)d_in[13];
  const float* skip_up_W    = (const float*)d_in[14];
  const float* highway_scale= (const float*)d_in[15];
  const float* out_W        = (const float*)d_in[16];
  float* out = (float*)d_out;
  float* ws = (float*)d_ws;

  // ---- f32 region ----
  float* theta_tab = ws;                                  // 3072
  float* w_tab     = theta_tab + 3072;                    // 3072
  float* slopes_sp = w_tab + 3072;                        // 16
  float* z_pre     = slopes_sp + 16;                      // 3,194,880
  float* gatelin   = z_pre + (size_t)NTOK_ * ZC_;         // 49,152
  float* csums     = gatelin + (size_t)NTOK_ * K_;        // 787,968
  float* cpre      = csums + (size_t)B_ * K_ * NC_ * 513; // 787,968
  _Float16* q_h    = (_Float16*)(cpre + (size_t)B_ * K_ * NC_ * 513); // 4096x3072
  _Float16* y_h    = q_h + (size_t)NTOK_ * QST_;          // 4096x2304
  float* f32_end   = (float*)(y_h + (size_t)NTOK_ * 2304);

  // split-K partials (3 x 4096 x 768 f32 = 9.44M floats) OVERLAY the dead
  // scan workspace (z_pre..q_h = 11.1M floats, consumed before outproj runs)
  float* part = z_pre;

  // ---- fp16 region ----
  _Float16* fp = (_Float16*)f32_end;
  _Float16* x_h    = fp;                fp += (size_t)NTOK_ * D_;
  _Float16* xpb_h  = fp;                fp += (size_t)XPN_ * 768;   // merged proj B (4096 rows)
  _Float16* outw_h = fp;                fp += (size_t)768 * 2304;
  _Float16* asp2_h = fp;                fp += (size_t)K_ * NTOK_ * 128;
  _Float16* bsp_h  = fp;                fp += (size_t)K_ * 384 * 320;
  _Float16* lat_h  = fp;                fp += (size_t)NTOK_ * 192;

  // fused prologue: precomp + all weight conversions (incl gate_W) + x->fp16
  prep_kernel<<<18651, 256, 0, stream>>>(x, W_mem, W_q, skip_down_W, out_W, W_re, W_im,
                                         skip_up_W, highway_scale, gate_W,
                                         theta_d_raw, decay_slopes,
                                         x_h, xpb_h, outw_h, bsp_h,
                                         theta_tab, w_tab, slopes_sp);

  // merged x-projection (256-tile 8-phase): q + lat + gate + z_pre in ONE dispatch
  xproj256_kernel<<<256, 512, 0, stream>>>(x_h, xpb_h, z_pre, lat_h, q_h, gatelin);

  // chunked scan (f32) with fused causal conv
  pass_a_kernel<<<dim3(NC_, K_, B_), 256, 0, stream>>>(z_pre, conv_k, theta_tab, score_scale,
                                                       tanh_scale, slopes_sp, csums);
  pass_b_kernel<<<dim3(9, B_ * K_), 64, 0, stream>>>(csums, cpre);
  pass_c_kernel<<<dim3(NC_, K_, B_), 256, 0, stream>>>(z_pre, conv_k, q_h, theta_tab, w_tab,
                                                       score_scale, tanh_scale, slopes_sp, cpre,
                                                       gatelin, gate_b, norm_scale, asp2_h);

  // batched spec GEMM (A = [asp2 per-k | lat_h shared], hs folded into bsp)
  // with fused SiLU -> y_h fp16; XCD-chunked 1D grid (3x32x12 blocks)
  spec_gemm_kernel<<<1152, 256, 0, stream>>>(asp2_h, bsp_h, lat_h, y_h);

  // out = y @ out_W: 256-tile 8-phase, split-K=4 via partial buffers (no atomics)
  outproj256_kernel<<<192, 512, 0, stream>>>(y_h, outw_h, out, part);
  // fold partials into out
  redout_kernel<<<3072, 256, 0, stream>>>(out, part);
}